// Round 12
// baseline (861.357 us; speedup 1.0000x reference)
//
#include <hip/hip_runtime.h>
#include <math.h>

#define BB 2
#define CC 256
#define HW 96
#define PP 9216
#define KO 18
#define HEADS 8
#define NCH 18

typedef short bf16x8 __attribute__((ext_vector_type(8)));
typedef float f32x4 __attribute__((ext_vector_type(4)));

// ws layout (float offsets), lifetime-aliased
#define NP_O    0UL          // norm partials 4*144*256 = 147456
#define W2_O    147456UL     // W2 hi+lo (2 batches) = 131072 -> ends 278528
#define IDX_O   331776UL     // int4 table 663552 (dead after dconv)
#define WGT_O   995328UL     // float4 table 663552 (dead after dconv)
#define WT2_O   1658880UL    // wt2 hi+lo = 589824 (dead after dconv)
#define WP2_O   2248704UL    // wp2 hi+lo = 73728 (dead after pconv)
#define WQ2_O   2322432UL    // wq2 hi+lo = 131072 (dead after qkv)
#define QP_O    2584576UL    // qpart 9437184 (aliases ppart; dead after attn_part)
#define KV_O    12021760UL   // k,v fp32 2*512*9216 = 9437184
#define AP_O    21459968UL   // attn partials 2*8*18*1024 = 294912
// v2t (bf16 hi+lo of v, tiled): aliases dead tables/weights/qpart-head
#define V2T_O   331776UL

__device__ __forceinline__ ushort f2bf_rne(float f) {
    unsigned u = __float_as_uint(f);
    unsigned r = (u + 0x7FFFu + ((u >> 16) & 1u)) >> 16;
    return (ushort)r;
}
__device__ __forceinline__ float bf2f(ushort h) {
    return __uint_as_float(((unsigned)h) << 16);
}

// ---- prep: wd[o][c][kk] -> wt2 hi/lo [kk][csg][(oh*64 + lhi*16 + lrow)]*8 ----
__global__ __launch_bounds__(256) void k_prep_wt(const float* __restrict__ wd,
                                                 ushort* __restrict__ h,
                                                 ushort* __restrict__ lo) {
    int tid = blockIdx.x * 256 + threadIdx.x;
    if (tid >= 9 * 8 * 1024 * 8) return;
    int e = tid & 7;
    int u = (tid >> 3) & 1023;
    int cs = (tid >> 13) & 7;
    int kk = tid >> 16;
    int oh = u >> 6, rem = u & 63;
    int lrow = rem & 15, lhi = rem >> 4;
    int o = oh * 16 + lrow;
    int c = cs * 32 + lhi * 8 + e;
    float v = wd[o * 2304 + c * 9 + kk];
    ushort hh = f2bf_rne(v);
    h[tid] = hh;
    lo[tid] = f2bf_rne(v - bf2f(hh));
}

// ---- prep: wp (o<18, pad to 32) -> wp2 hi/lo, identity lane layout ----
__global__ __launch_bounds__(256) void k_prep_wp(const float* __restrict__ wp,
                                                 ushort* __restrict__ h,
                                                 ushort* __restrict__ lo) {
    int tid = blockIdx.x * 256 + threadIdx.x;
    if (tid >= 9 * 8 * 128 * 8) return;
    int e = tid & 7;
    int u = (tid >> 3) & 127;
    int cs = (tid >> 10) & 7;
    int kk = tid >> 13;
    int mf = u >> 6, rem = u & 63;
    int lrow = rem & 15, lhi = rem >> 4;
    int o = mf * 16 + lrow;
    int c = cs * 32 + lhi * 8 + e;
    float v = (o < KO) ? wp[(o * 256 + c) * 9 + kk] : 0.f;
    ushort hh = f2bf_rne(v);
    h[tid] = hh;
    lo[tid] = f2bf_rne(v - bf2f(hh));
}

// ---- prep generic weight W[M][256] -> [mt][csg][u]*8 hi/lo, identity lane layout ----
__global__ __launch_bounds__(256) void k_prep_w(const float* __restrict__ W,
                                                ushort* __restrict__ h,
                                                ushort* __restrict__ lo,
                                                int total) {
    int tid = blockIdx.x * 256 + threadIdx.x;
    if (tid >= total) return;
    int e = tid & 7;
    int u = (tid >> 3) & 1023;
    int csg = (tid >> 13) & 7;
    int mt = tid >> 16;
    int rem = u & 63;
    int lrow = rem & 15, lhi = rem >> 4;
    int o = mt * 256 + (u >> 6) * 16 + lrow;
    int c = csg * 32 + lhi * 8 + e;
    float v = W[o * 256 + c];
    ushort hh = f2bf_rne(v);
    h[tid] = hh;
    lo[tid] = f2bf_rne(v - bf2f(hh));
}

// ---- pconv MFMA, XCD-swizzled 1D grid of 1152 ----
__global__ __launch_bounds__(256) void k_pconv(const float* __restrict__ x,
                                               const ushort* __restrict__ wp2h,
                                               const ushort* __restrict__ wp2l,
                                               float* __restrict__ ppart) {
    int s = blockIdx.x;
    int xcd = s & 7;
    int b = xcd & 1, ks = xcd >> 1;
    int p0 = (s >> 3) * 64;
    int t = threadIdx.x;
    int l = t & 63, w = t >> 6;
    int lrow = l & 15, lhi = l >> 4;
    int p = t & 63, cg = t >> 6;
    __shared__ __align__(16) ushort Sh[64 * 40];
    __shared__ __align__(16) ushort Sl[64 * 40];
    f32x4 acc[2];
    acc[0] = (f32x4)0.f; acc[1] = (f32x4)0.f;
    const float* xb = x + (size_t)b * CC * PP;
    int pix = p0 + p;
    int i_ = pix / 96, j_ = pix % 96;
#pragma unroll 1
    for (int cs = 0; cs < 2; ++cs) {
        int csg = ks * 2 + cs;
        const float* xc0 = xb + (size_t)(csg * 32 + cg * 8) * PP;
#pragma unroll 1
        for (int kk = 0; kk < 9; ++kk) {
            int di = kk / 3 - 1, dj = kk % 3 - 1;
            bool vOK = ((unsigned)(i_ + di) < 96u) && ((unsigned)(j_ + dj) < 96u);
            int poff = pix + di * 96 + dj;
            __syncthreads();
            bf16x8 ah[2], al[2];
#pragma unroll
            for (int mf = 0; mf < 2; ++mf) {
                size_t gi = (((size_t)(kk * 8 + csg)) * 128 + (mf * 64 + l)) * 8;
                ah[mf] = *(const bf16x8*)&wp2h[gi];
                al[mf] = *(const bf16x8*)&wp2l[gi];
            }
            bf16x8 vh, vl;
#pragma unroll
            for (int i = 0; i < 8; ++i) {
                float v = vOK ? xc0[(size_t)i * PP + poff] : 0.f;
                ushort hh = f2bf_rne(v);
                vh[i] = (short)hh;
                vl[i] = (short)f2bf_rne(v - bf2f(hh));
            }
            *(bf16x8*)&Sh[p * 40 + cg * 8] = vh;
            *(bf16x8*)&Sl[p * 40 + cg * 8] = vl;
            __syncthreads();
            bf16x8 Bh = *(const bf16x8*)&Sh[(w * 16 + lrow) * 40 + lhi * 8];
            bf16x8 Bl = *(const bf16x8*)&Sl[(w * 16 + lrow) * 40 + lhi * 8];
#pragma unroll
            for (int mf = 0; mf < 2; ++mf) {
                acc[mf] = __builtin_amdgcn_mfma_f32_16x16x32_bf16(ah[mf], Bh, acc[mf], 0, 0, 0);
                acc[mf] = __builtin_amdgcn_mfma_f32_16x16x32_bf16(ah[mf], Bl, acc[mf], 0, 0, 0);
                acc[mf] = __builtin_amdgcn_mfma_f32_16x16x32_bf16(al[mf], Bh, acc[mf], 0, 0, 0);
            }
        }
    }
    float* pr = ppart + ((size_t)(ks * BB + b) * 32) * PP;
#pragma unroll
    for (int mf = 0; mf < 2; ++mf)
#pragma unroll
        for (int j = 0; j < 4; ++j)
            pr[(size_t)(mf * 16 + lhi * 4 + j) * PP + p0 + w * 16 + lrow] = acc[mf][j];
}

// ---- bilinear table (fused partial-reduce + bias + bilin math) ----
__global__ __launch_bounds__(256) void k_bilin2(const float* __restrict__ pp,
                                                const float* __restrict__ bp,
                                                int4* __restrict__ idx4,
                                                float4* __restrict__ wgt4) {
    int idx = blockIdx.x * 256 + threadIdx.x;
    if (idx >= BB * 9 * PP) return;
    int p = idx % PP;
    int bn = idx / PP;
    int n = bn % 9, b = bn / 9;
    int i = p / 96, j = p % 96;
    float ox = bp[n], oy = bp[n + 9];
#pragma unroll
    for (int k = 0; k < 4; ++k) {
        ox += pp[((size_t)(k * BB + b) * 32 + n) * PP + p];
        oy += pp[((size_t)(k * BB + b) * 32 + n + 9) * PP + p];
    }
    float px = ox + (float)(n / 3 - 1) + (float)(i + 1);
    float py = oy + (float)(n % 3 - 1) + (float)(j + 1);
    float fx = floorf(px), fy = floorf(py);
    float qltx = fminf(fmaxf(fx, 0.f), 97.f);
    float qlty = fminf(fmaxf(fy, 0.f), 97.f);
    float qrbx = fminf(fmaxf(fx + 1.f, 0.f), 97.f);
    float qrby = fminf(fmaxf(fy + 1.f, 0.f), 97.f);
    float pxc = fminf(fmaxf(px, 0.f), 97.f);
    float pyc = fminf(fmaxf(py, 0.f), 97.f);
    float glt = (1.f + (qltx - pxc)) * (1.f + (qlty - pyc));
    float grb = (1.f - (qrbx - pxc)) * (1.f - (qrby - pyc));
    float glb = (1.f + (qltx - pxc)) * (1.f - (qrby - pyc));
    float grt = (1.f - (qrbx - pxc)) * (1.f + (qlty - pyc));
    int x0 = (int)qltx - 1, y0 = (int)qlty - 1;
    int x1 = (int)qrbx - 1, y1 = (int)qrby - 1;
    bool vlt = (x0 >= 0 && x0 < 96 && y0 >= 0 && y0 < 96);
    bool vrb = (x1 >= 0 && x1 < 96 && y1 >= 0 && y1 < 96);
    bool vlb = (x0 >= 0 && x0 < 96 && y1 >= 0 && y1 < 96);
    bool vrt = (x1 >= 0 && x1 < 96 && y0 >= 0 && y0 < 96);
    int4 id;
    id.x = vlt ? x0 * 96 + y0 : 0;
    id.y = vrb ? x1 * 96 + y1 : 0;
    id.z = vlb ? x0 * 96 + y1 : 0;
    id.w = vrt ? x1 * 96 + y0 : 0;
    idx4[idx] = id;
    wgt4[idx] = make_float4(vlt ? glt : 0.f, vrb ? grb : 0.f,
                            vlb ? glb : 0.f, vrt ? grt : 0.f);
}

// ---- deformable conv MFMA: wave-independent, NO LDS, NO barriers ----
// Lane l gathers exactly its B-fragment {pixel=lane&15, c=(lane>>4)*8+e}.
// Each wave: 16 pixels x all 256 o (16 m-frags). Grid 576, 4 waves/block.
__global__ __launch_bounds__(256) void k_dconv(const float* __restrict__ x,
                                               const ushort* __restrict__ wt2h,
                                               const ushort* __restrict__ wt2l,
                                               const int4* __restrict__ idx4,
                                               const float4* __restrict__ wgt4,
                                               float* __restrict__ qpart) {
    int s = blockIdx.x;
    int xcd = s & 7, ib = s >> 3;
    int combo = xcd >> 1;
    int b = combo & 1;
    int half = combo >> 1;
    int ptile = (xcd & 1) * 72 + ib;
    int p0 = ptile * 64;
    int t = threadIdx.x;
    int w = t >> 6, l = t & 63;
    int lrow = l & 15, lhi = l >> 4;
    int mypix = p0 + w * 16 + lrow;

    const float* xb = x + (size_t)b * CC * PP;
    int h4 = half * 4;

    f32x4 acc[16];
#pragma unroll
    for (int mf = 0; mf < 16; ++mf) acc[mf] = (f32x4)0.f;

    float R0[32], R1[32];
    float4 g0, g1;

    auto LD = [&](int i, float (&R)[32], float4& g) {
        int cs = i / 9, kk = i % 9;
        int csg = h4 + cs;
        size_t tb = ((size_t)b * 9 + kk) * PP + mypix;
        int4 id = idx4[tb];
        g = wgt4[tb];
        const float* xc0 = xb + (size_t)(csg * 32 + lhi * 8) * PP;
#pragma unroll
        for (int e = 0; e < 8; ++e) {
            const float* xc = xc0 + (size_t)e * PP;
            R[e * 4 + 0] = xc[id.x];
            R[e * 4 + 1] = xc[id.y];
            R[e * 4 + 2] = xc[id.z];
            R[e * 4 + 3] = xc[id.w];
        }
    };
    auto CONV = [&](const float (&R)[32], float4 g, bf16x8& bh, bf16x8& bl) {
#pragma unroll
        for (int e = 0; e < 8; ++e) {
            float v = g.x * R[e * 4 + 0];
            v = fmaf(g.y, R[e * 4 + 1], v);
            v = fmaf(g.z, R[e * 4 + 2], v);
            v = fmaf(g.w, R[e * 4 + 3], v);
            ushort hh = f2bf_rne(v);
            bh[e] = (short)hh;
            bl[e] = (short)f2bf_rne(v - bf2f(hh));
        }
    };
    auto MM = [&](int i, bf16x8 bh, bf16x8 bl) {
        int cs = i / 9, kk = i % 9;
        int csg = h4 + cs;
        const ushort* ah0 = wt2h + ((size_t)(kk * 8 + csg)) * 8192;
        const ushort* al0 = wt2l + ((size_t)(kk * 8 + csg)) * 8192;
#pragma unroll
        for (int mf = 0; mf < 16; ++mf) {
            bf16x8 ah = *(const bf16x8*)&ah0[(size_t)(mf * 64 + l) * 8];
            bf16x8 al = *(const bf16x8*)&al0[(size_t)(mf * 64 + l) * 8];
            acc[mf] = __builtin_amdgcn_mfma_f32_16x16x32_bf16(ah, bh, acc[mf], 0, 0, 0);
            acc[mf] = __builtin_amdgcn_mfma_f32_16x16x32_bf16(ah, bl, acc[mf], 0, 0, 0);
            acc[mf] = __builtin_amdgcn_mfma_f32_16x16x32_bf16(al, bh, acc[mf], 0, 0, 0);
        }
    };

    LD(0, R0, g0);
    LD(1, R1, g1);
#pragma unroll 1
    for (int i0 = 0; i0 < 36; i0 += 2) {
        {
            bf16x8 bh, bl;
            CONV(R0, g0, bh, bl);
            if (i0 + 2 < 36) LD(i0 + 2, R0, g0);   // gathers drain under MM
            MM(i0, bh, bl);
        }
        {
            bf16x8 bh, bl;
            CONV(R1, g1, bh, bl);
            if (i0 + 3 < 36) LD(i0 + 3, R1, g1);
            MM(i0 + 1, bh, bl);
        }
    }

    float* qh = qpart + (size_t)half * BB * CC * PP + (size_t)b * CC * PP;
#pragma unroll
    for (int mf = 0; mf < 16; ++mf)
#pragma unroll
        for (int j = 0; j < 4; ++j)
            qh[(size_t)(mf * 16 + lhi * 4 + j) * PP + mypix] = acc[mf][j];
}

// ---- generic MFMA GEMM; B from fp32 (convert) or pre-split bf16 planes ----
__global__ __launch_bounds__(256) void k_gemm_bf(const float* __restrict__ Bsrc,
                                                 const ushort* __restrict__ B2h,
                                                 const ushort* __restrict__ B2l,
                                                 const ushort* __restrict__ A2h,
                                                 const ushort* __restrict__ A2l,
                                                 float* __restrict__ C,
                                                 int mtiles, int bRowStride, int bRowOff,
                                                 int aBatchStride,
                                                 float* __restrict__ npart) {
    int s = blockIdx.x;
    int xcd = s & 7, ib = s >> 3;
    int b, mt, ptile;
    if (mtiles == 2) {
        int combo = xcd >> 1;
        b = combo & 1; mt = combo >> 1;
        ptile = (xcd & 1) * 72 + ib;
    } else {
        b = xcd >> 2; mt = 0;
        ptile = (xcd & 3) * 36 + ib;
    }
    int p0 = ptile * 64;
    int t = threadIdx.x;
    int l = t & 63, w = t >> 6;
    int lrow = l & 15, lhi = l >> 4;
    int obase = w * 64;
    int p = t & 63, cg = t >> 6;
    __shared__ __align__(16) ushort Sh[64 * 40];
    __shared__ __align__(16) ushort Sl[64 * 40];
    f32x4 acc[4][4];
#pragma unroll
    for (int mf = 0; mf < 4; ++mf)
#pragma unroll
        for (int nf = 0; nf < 4; ++nf) acc[mf][nf] = (f32x4)0.f;
    const ushort* Ah = A2h + (size_t)b * aBatchStride;
    const ushort* Al = A2l + (size_t)b * aBatchStride;
#pragma unroll 1
    for (int csg = 0; csg < 8; ++csg) {
        __syncthreads();
        bf16x8 ah[4], al[4];
#pragma unroll
        for (int mf = 0; mf < 4; ++mf) {
            size_t gi = (((size_t)(mt * 8 + csg)) * 1024 + ((w * 4 + mf) * 64 + l)) * 8;
            ah[mf] = *(const bf16x8*)&Ah[gi];
            al[mf] = *(const bf16x8*)&Al[gi];
        }
        if (B2h) {
            size_t bo = ((((size_t)b * 144 + ptile) * 8 + csg) * 4 + cg) * 512 + (size_t)p * 8;
            bf16x8 vh = *(const bf16x8*)&B2h[bo];
            bf16x8 vl = *(const bf16x8*)&B2l[bo];
            *(bf16x8*)&Sh[p * 40 + cg * 8] = vh;
            *(bf16x8*)&Sl[p * 40 + cg * 8] = vl;
        } else {
            const float* Bb = Bsrc + ((size_t)b * bRowStride + bRowOff) * PP;
            const float* xr = Bb + (size_t)(csg * 32 + cg * 8) * PP + p0 + p;
            bf16x8 vh, vl;
#pragma unroll
            for (int i = 0; i < 8; ++i) {
                float v = xr[(size_t)i * PP];
                ushort hh = f2bf_rne(v);
                vh[i] = (short)hh;
                vl[i] = (short)f2bf_rne(v - bf2f(hh));
            }
            *(bf16x8*)&Sh[p * 40 + cg * 8] = vh;
            *(bf16x8*)&Sl[p * 40 + cg * 8] = vl;
        }
        __syncthreads();
        bf16x8 Bh4[4], Bl4[4];
#pragma unroll
        for (int nf = 0; nf < 4; ++nf) {
            Bh4[nf] = *(const bf16x8*)&Sh[(nf * 16 + lrow) * 40 + lhi * 8];
            Bl4[nf] = *(const bf16x8*)&Sl[(nf * 16 + lrow) * 40 + lhi * 8];
        }
#pragma unroll
        for (int mf = 0; mf < 4; ++mf) {
#pragma unroll
            for (int nf = 0; nf < 4; ++nf) {
                acc[mf][nf] = __builtin_amdgcn_mfma_f32_16x16x32_bf16(ah[mf], Bh4[nf], acc[mf][nf], 0, 0, 0);
                acc[mf][nf] = __builtin_amdgcn_mfma_f32_16x16x32_bf16(ah[mf], Bl4[nf], acc[mf][nf], 0, 0, 0);
                acc[mf][nf] = __builtin_amdgcn_mfma_f32_16x16x32_bf16(al[mf], Bh4[nf], acc[mf][nf], 0, 0, 0);
            }
        }
    }
    float* Cb = C + (size_t)b * (mtiles * 256) * PP;
#pragma unroll
    for (int mf = 0; mf < 4; ++mf)
#pragma unroll
        for (int nf = 0; nf < 4; ++nf)
#pragma unroll
            for (int j = 0; j < 4; ++j)
                Cb[(size_t)(mt * 256 + obase + mf * 16 + lhi * 4 + j) * PP + p0 + nf * 16 + lrow] =
                    acc[mf][nf][j];
    if (npart) {
        float sq[4][4];
#pragma unroll
        for (int mf = 0; mf < 4; ++mf)
#pragma unroll
            for (int j = 0; j < 4; ++j) {
                float v0 = acc[mf][0][j], v1 = acc[mf][1][j];
                float v2 = acc[mf][2][j], v3 = acc[mf][3][j];
                sq[mf][j] = v0 * v0 + v1 * v1 + v2 * v2 + v3 * v3;
            }
#pragma unroll
        for (int m = 1; m <= 8; m <<= 1)
#pragma unroll
            for (int mf = 0; mf < 4; ++mf)
#pragma unroll
                for (int j = 0; j < 4; ++j)
                    sq[mf][j] += __shfl_xor(sq[mf][j], m, 64);
        if (lrow == 0) {
            float* np = npart + ((size_t)(b * 2 + mt) * 144 + ptile) * 256;
#pragma unroll
            for (int mf = 0; mf < 4; ++mf)
#pragma unroll
                for (int j = 0; j < 4; ++j)
                    np[obase + mf * 16 + lhi * 4 + j] = sq[mf][j];
        }
    }
}

// ---- v (fp32, kv second half) -> v2t bf16 hi/lo tiled [b][pt][csg][cc][pl][e] ----
__global__ __launch_bounds__(256) void k_prep_v(const float* __restrict__ kv,
                                                ushort* __restrict__ v2h,
                                                ushort* __restrict__ v2l) {
    int s = blockIdx.x;              // 2304 = 2b * 144pt * 8csg
    int b = s / 1152;
    int r = s % 1152;
    int pt = r >> 3, csg = r & 7;
    int t = threadIdx.x;
    __shared__ float T[32][65];
    const float* src = kv + ((size_t)b * 512 + 256 + csg * 32) * PP + pt * 64;
    {
        int c = t >> 3, p8 = (t & 7) * 8;
        const float* row = src + (size_t)c * PP + p8;
        float4 a = *(const float4*)&row[0];
        float4 d = *(const float4*)&row[4];
        T[c][p8 + 0] = a.x; T[c][p8 + 1] = a.y; T[c][p8 + 2] = a.z; T[c][p8 + 3] = a.w;
        T[c][p8 + 4] = d.x; T[c][p8 + 5] = d.y; T[c][p8 + 6] = d.z; T[c][p8 + 7] = d.w;
    }
    __syncthreads();
    int cc = t >> 6, pl = t & 63;
    bf16x8 vh, vl;
#pragma unroll
    for (int e = 0; e < 8; ++e) {
        float v = T[cc * 8 + e][pl];
        ushort hh = f2bf_rne(v);
        vh[e] = (short)hh;
        vl[e] = (short)f2bf_rne(v - bf2f(hh));
    }
    size_t o = ((((size_t)b * 144 + pt) * 8 + csg) * 4 + cc) * 512 + (size_t)pl * 8;
    *(bf16x8*)&v2h[o] = vh;
    *(bf16x8*)&v2l[o] = vl;
}

// ---- attention score partials: q . k over 512-p chunks (NCH=18) ----
__global__ __launch_bounds__(256) void k_attn_part(const float* __restrict__ qp,
                                                   const float* __restrict__ kv,
                                                   float* __restrict__ apart) {
    int ch = blockIdx.x, h = blockIdx.y, b = blockIdx.z;
    int t = threadIdx.x;
    int d = t & 31, cg = t >> 5;
    __shared__ float qs[32][37], ks[32][37];
    float acc[4] = {0.f, 0.f, 0.f, 0.f};
    const float* q0 = qp + ((size_t)b * CC + h * 32) * PP;
    const float* q1 = q0 + (size_t)BB * CC * PP;
    const float* kb = kv + ((size_t)b * 512 + h * 32) * PP;
    int r = t >> 3, cq = (t & 7) * 4;
    for (int po = ch * 512; po < ch * 512 + 512; po += 32) {
        float4 va = *(const float4*)&q0[(size_t)r * PP + po + cq];
        float4 vb = *(const float4*)&q1[(size_t)r * PP + po + cq];
        qs[r][cq + 0] = va.x + vb.x; qs[r][cq + 1] = va.y + vb.y;
        qs[r][cq + 2] = va.z + vb.z; qs[r][cq + 3] = va.w + vb.w;
        float4 vk = *(const float4*)&kb[(size_t)r * PP + po + cq];
        ks[r][cq + 0] = vk.x; ks[r][cq + 1] = vk.y;
        ks[r][cq + 2] = vk.z; ks[r][cq + 3] = vk.w;
        __syncthreads();
#pragma unroll
        for (int pq = 0; pq < 32; ++pq) {
            float kvv = ks[d][pq];
#pragma unroll
            for (int i = 0; i < 4; ++i)
                acc[i] = fmaf(qs[cg * 4 + i][pq], kvv, acc[i]);
        }
        __syncthreads();
    }
    float* ap = apart + (((size_t)(b * 8 + h) * NCH + ch) << 10);
#pragma unroll
    for (int i = 0; i < 4; ++i) ap[(cg * 4 + i) * 32 + d] = acc[i];
}

// ---- merged: norms + reduce + softmax + W2 = Wproj-slice @ As ----
__global__ __launch_bounds__(256) void k_attn_fin_w2(const float* __restrict__ apart,
                                                     const float* __restrict__ npart,
                                                     const float* __restrict__ temp,
                                                     const float* __restrict__ wproj,
                                                     ushort* __restrict__ w2h,
                                                     ushort* __restrict__ w2l) {
    int h = blockIdx.x, b = blockIdx.y;
    int t = threadIdx.x;
    __shared__ float A[32][33];
    __shared__ float invk[32], invv[32];
    if (t < 64) {
        int mt = t >> 5, row = (t & 31) + h * 32;
        const float* base = npart + ((size_t)(b * 2 + mt) * 144) * 256 + row;
        float ssum = 0.f;
        for (int pt = 0; pt < 144; ++pt) ssum += base[pt * 256];
        float iv = 1.f / fmaxf(sqrtf(ssum), 1e-12f);
        if (mt == 0) invk[t & 31] = iv; else invv[t & 31] = iv;
    }
    const float* ap = apart + ((size_t)(b * 8 + h) * NCH << 10);
    float th = temp[h];
    for (int e = t; e < 1024; e += 256) {
        float s = 0.f;
        for (int chn = 0; chn < NCH; ++chn) s += ap[chn * 1024 + e];
        A[e >> 5][e & 31] = s * th;
    }
    __syncthreads();
    if (t < 32) {
        int c = t;
        float m = -INFINITY;
        float row[32];
#pragma unroll
        for (int d = 0; d < 32; ++d) {
            row[d] = A[c][d] * invk[d];
            m = fmaxf(m, row[d]);
        }
        float sum = 0.f;
#pragma unroll
        for (int d = 0; d < 32; ++d) sum += expf(row[d] - m);
        float inv = 1.f / sum;
#pragma unroll
        for (int d = 0; d < 32; ++d)
            A[c][d] = expf(row[d] - m) * inv * invv[d];
    }
    __syncthreads();
    int o = t;
    float wrow[32];
#pragma unroll
    for (int c = 0; c < 32; ++c) wrow[c] = wproj[o * 256 + h * 32 + c];
    int wq = o >> 6, mf = (o >> 4) & 3, lr = o & 15;
    size_t bb = (size_t)b * 65536;
#pragma unroll
    for (int e = 0; e < 32; ++e) {
        float v = 0.f;
#pragma unroll
        for (int c = 0; c < 32; ++c) v = fmaf(wrow[c], A[c][e], v);
        int lhi = e >> 3, ee = e & 7;
        size_t gi = bb + ((size_t)h * 1024 + ((wq * 4 + mf) * 64 + lhi * 16 + lr)) * 8 + ee;
        ushort hh = f2bf_rne(v);
        w2h[gi] = hh;
        w2l[gi] = f2bf_rne(v - bf2f(hh));
    }
}

extern "C" void kernel_launch(void* const* d_in, const int* in_sizes, int n_in,
                              void* d_out, int out_size, void* d_ws, size_t ws_size,
                              hipStream_t stream) {
    const float* x     = (const float*)d_in[0];
    const float* wp    = (const float*)d_in[1];
    const float* bp    = (const float*)d_in[2];
    const float* wd    = (const float*)d_in[3];
    const float* wqkv  = (const float*)d_in[4];
    const float* temp  = (const float*)d_in[5];
    const float* wproj = (const float*)d_in[6];
    float* out = (float*)d_out;
    float* ws  = (float*)d_ws;

    float* npart  = ws + NP_O;
    ushort* w2h   = (ushort*)(ws + W2_O);
    ushort* w2l   = w2h + 2 * 65536;
    int4*  idx4   = (int4*)(ws + IDX_O);
    float4* wgt4  = (float4*)(ws + WGT_O);
    ushort* wt2h  = (ushort*)(ws + WT2_O);
    ushort* wt2l  = wt2h + 9 * 8 * 1024 * 8;
    ushort* wp2h  = (ushort*)(ws + WP2_O);
    ushort* wp2l  = wp2h + 9 * 8 * 128 * 8;
    ushort* wq2h  = (ushort*)(ws + WQ2_O);
    ushort* wq2l  = wq2h + 2 * 8 * 1024 * 8;
    float* qpart  = ws + QP_O;   // aliases ppart (sequential lifetimes)
    float* ppart  = ws + QP_O;
    float* kv     = ws + KV_O;
    float* apart  = ws + AP_O;
    ushort* v2th  = (ushort*)(ws + V2T_O);   // aliases dead tables/weights/qpart-head
    ushort* v2tl  = v2th + 4718592;

    k_prep_wt<<<2304, 256, 0, stream>>>(wd, wt2h, wt2l);
    k_prep_wp<<<288, 256, 0, stream>>>(wp, wp2h, wp2l);
    k_prep_w<<<512, 256, 0, stream>>>(wqkv + 256 * 256, wq2h, wq2l, 2 * 65536);
    k_pconv<<<1152, 256, 0, stream>>>(x, wp2h, wp2l, ppart);
    k_bilin2<<<(BB * 9 * PP + 255) / 256, 256, 0, stream>>>(ppart, bp, idx4, wgt4);
    k_dconv<<<576, 256, 0, stream>>>(x, wt2h, wt2l, idx4, wgt4, qpart);
    k_gemm_bf<<<576, 256, 0, stream>>>(x, nullptr, nullptr, wq2h, wq2l, kv,
                                       2, 256, 0, 0, npart);
    k_attn_part<<<dim3(NCH, HEADS, BB), 256, 0, stream>>>(qpart, kv, apart);
    k_attn_fin_w2<<<dim3(HEADS, BB), 256, 0, stream>>>(apart, npart, temp, wproj, w2h, w2l);
    k_prep_v<<<2304, 256, 0, stream>>>(kv, v2th, v2tl);
    k_gemm_bf<<<288, 256, 0, stream>>>(nullptr, v2th, v2tl, w2h, w2l, out,
                                       1, 0, 0, 65536, nullptr);
}

// Round 13
// 300.543 us; speedup vs baseline: 2.8660x; 2.8660x over previous
//
#include <hip/hip_runtime.h>
#include <math.h>

#define BB 2
#define CC 256
#define HW 96
#define PP 9216
#define KO 18
#define HEADS 8
#define NCH 18

typedef short bf16x8 __attribute__((ext_vector_type(8)));
typedef float f32x4 __attribute__((ext_vector_type(4)));

// ws layout (float offsets), lifetime-aliased
#define NP_O    0UL          // norm partials 4*144*256 = 147456
#define W2_O    147456UL     // W2 hi+lo (2 batches) = 131072 -> ends 278528
#define IDX_O   331776UL     // int4 table 663552 (dead after dconv)
#define WGT_O   995328UL     // float4 table 663552 (dead after dconv)
#define WT2_O   1658880UL    // wt2 hi+lo = 589824 (dead after dconv)
#define WP2_O   2248704UL    // wp2 hi+lo = 73728 (dead after pconv)
#define WQ2_O   2322432UL    // wq2 hi+lo = 131072 (dead after qkv)
#define QP_O    2584576UL    // qpart 9437184 (aliases ppart; dead after attn_part)
#define KV_O    12021760UL   // k,v fp32 2*512*9216 = 9437184
#define AP_O    21459968UL   // attn partials 2*8*18*1024 = 294912

__device__ __forceinline__ ushort f2bf_rne(float f) {
    unsigned u = __float_as_uint(f);
    unsigned r = (u + 0x7FFFu + ((u >> 16) & 1u)) >> 16;
    return (ushort)r;
}
__device__ __forceinline__ float bf2f(ushort h) {
    return __uint_as_float(((unsigned)h) << 16);
}

// ---- prep: wd[o][c][kk] -> wt2 hi/lo [kk][csg][(oh*64 + lhi*16 + lrow)]*8 ----
__global__ __launch_bounds__(256) void k_prep_wt(const float* __restrict__ wd,
                                                 ushort* __restrict__ h,
                                                 ushort* __restrict__ lo) {
    int tid = blockIdx.x * 256 + threadIdx.x;
    if (tid >= 9 * 8 * 1024 * 8) return;
    int e = tid & 7;
    int u = (tid >> 3) & 1023;
    int cs = (tid >> 13) & 7;
    int kk = tid >> 16;
    int oh = u >> 6, rem = u & 63;
    int lrow = rem & 15, lhi = rem >> 4;
    int o = oh * 16 + lrow;
    int c = cs * 32 + lhi * 8 + e;
    float v = wd[o * 2304 + c * 9 + kk];
    ushort hh = f2bf_rne(v);
    h[tid] = hh;
    lo[tid] = f2bf_rne(v - bf2f(hh));
}

// ---- prep: wp (o<18, pad to 32) -> wp2 hi/lo, identity lane layout ----
__global__ __launch_bounds__(256) void k_prep_wp(const float* __restrict__ wp,
                                                 ushort* __restrict__ h,
                                                 ushort* __restrict__ lo) {
    int tid = blockIdx.x * 256 + threadIdx.x;
    if (tid >= 9 * 8 * 128 * 8) return;
    int e = tid & 7;
    int u = (tid >> 3) & 127;
    int cs = (tid >> 10) & 7;
    int kk = tid >> 13;
    int mf = u >> 6, rem = u & 63;
    int lrow = rem & 15, lhi = rem >> 4;
    int o = mf * 16 + lrow;
    int c = cs * 32 + lhi * 8 + e;
    float v = (o < KO) ? wp[(o * 256 + c) * 9 + kk] : 0.f;
    ushort hh = f2bf_rne(v);
    h[tid] = hh;
    lo[tid] = f2bf_rne(v - bf2f(hh));
}

// ---- prep generic weight W[M][256] -> [mt][csg][u]*8 hi/lo, identity lane layout ----
__global__ __launch_bounds__(256) void k_prep_w(const float* __restrict__ W,
                                                ushort* __restrict__ h,
                                                ushort* __restrict__ lo,
                                                int total) {
    int tid = blockIdx.x * 256 + threadIdx.x;
    if (tid >= total) return;
    int e = tid & 7;
    int u = (tid >> 3) & 1023;
    int csg = (tid >> 13) & 7;
    int mt = tid >> 16;
    int rem = u & 63;
    int lrow = rem & 15, lhi = rem >> 4;
    int o = mt * 256 + (u >> 6) * 16 + lrow;
    int c = csg * 32 + lhi * 8 + e;
    float v = W[o * 256 + c];
    ushort hh = f2bf_rne(v);
    h[tid] = hh;
    lo[tid] = f2bf_rne(v - bf2f(hh));
}

// ---- pconv MFMA, XCD-swizzled 1D grid of 1152 ----
__global__ __launch_bounds__(256) void k_pconv(const float* __restrict__ x,
                                               const ushort* __restrict__ wp2h,
                                               const ushort* __restrict__ wp2l,
                                               float* __restrict__ ppart) {
    int s = blockIdx.x;
    int xcd = s & 7;
    int b = xcd & 1, ks = xcd >> 1;
    int p0 = (s >> 3) * 64;
    int t = threadIdx.x;
    int l = t & 63, w = t >> 6;
    int lrow = l & 15, lhi = l >> 4;
    int p = t & 63, cg = t >> 6;
    __shared__ __align__(16) ushort Sh[64 * 40];
    __shared__ __align__(16) ushort Sl[64 * 40];
    f32x4 acc[2];
    acc[0] = (f32x4)0.f; acc[1] = (f32x4)0.f;
    const float* xb = x + (size_t)b * CC * PP;
    int pix = p0 + p;
    int i_ = pix / 96, j_ = pix % 96;
#pragma unroll 1
    for (int cs = 0; cs < 2; ++cs) {
        int csg = ks * 2 + cs;
        const float* xc0 = xb + (size_t)(csg * 32 + cg * 8) * PP;
#pragma unroll 1
        for (int kk = 0; kk < 9; ++kk) {
            int di = kk / 3 - 1, dj = kk % 3 - 1;
            bool vOK = ((unsigned)(i_ + di) < 96u) && ((unsigned)(j_ + dj) < 96u);
            int poff = pix + di * 96 + dj;
            __syncthreads();
            bf16x8 ah[2], al[2];
#pragma unroll
            for (int mf = 0; mf < 2; ++mf) {
                size_t gi = (((size_t)(kk * 8 + csg)) * 128 + (mf * 64 + l)) * 8;
                ah[mf] = *(const bf16x8*)&wp2h[gi];
                al[mf] = *(const bf16x8*)&wp2l[gi];
            }
            bf16x8 vh, vl;
#pragma unroll
            for (int i = 0; i < 8; ++i) {
                float v = vOK ? xc0[(size_t)i * PP + poff] : 0.f;
                ushort hh = f2bf_rne(v);
                vh[i] = (short)hh;
                vl[i] = (short)f2bf_rne(v - bf2f(hh));
            }
            *(bf16x8*)&Sh[p * 40 + cg * 8] = vh;
            *(bf16x8*)&Sl[p * 40 + cg * 8] = vl;
            __syncthreads();
            bf16x8 Bh = *(const bf16x8*)&Sh[(w * 16 + lrow) * 40 + lhi * 8];
            bf16x8 Bl = *(const bf16x8*)&Sl[(w * 16 + lrow) * 40 + lhi * 8];
#pragma unroll
            for (int mf = 0; mf < 2; ++mf) {
                acc[mf] = __builtin_amdgcn_mfma_f32_16x16x32_bf16(ah[mf], Bh, acc[mf], 0, 0, 0);
                acc[mf] = __builtin_amdgcn_mfma_f32_16x16x32_bf16(ah[mf], Bl, acc[mf], 0, 0, 0);
                acc[mf] = __builtin_amdgcn_mfma_f32_16x16x32_bf16(al[mf], Bh, acc[mf], 0, 0, 0);
            }
        }
    }
    float* pr = ppart + ((size_t)(ks * BB + b) * 32) * PP;
#pragma unroll
    for (int mf = 0; mf < 2; ++mf)
#pragma unroll
        for (int j = 0; j < 4; ++j)
            pr[(size_t)(mf * 16 + lhi * 4 + j) * PP + p0 + w * 16 + lrow] = acc[mf][j];
}

// ---- bilinear table (fused partial-reduce + bias + bilin math) ----
__global__ __launch_bounds__(256) void k_bilin2(const float* __restrict__ pp,
                                                const float* __restrict__ bp,
                                                int4* __restrict__ idx4,
                                                float4* __restrict__ wgt4) {
    int idx = blockIdx.x * 256 + threadIdx.x;
    if (idx >= BB * 9 * PP) return;
    int p = idx % PP;
    int bn = idx / PP;
    int n = bn % 9, b = bn / 9;
    int i = p / 96, j = p % 96;
    float ox = bp[n], oy = bp[n + 9];
#pragma unroll
    for (int k = 0; k < 4; ++k) {
        ox += pp[((size_t)(k * BB + b) * 32 + n) * PP + p];
        oy += pp[((size_t)(k * BB + b) * 32 + n + 9) * PP + p];
    }
    float px = ox + (float)(n / 3 - 1) + (float)(i + 1);
    float py = oy + (float)(n % 3 - 1) + (float)(j + 1);
    float fx = floorf(px), fy = floorf(py);
    float qltx = fminf(fmaxf(fx, 0.f), 97.f);
    float qlty = fminf(fmaxf(fy, 0.f), 97.f);
    float qrbx = fminf(fmaxf(fx + 1.f, 0.f), 97.f);
    float qrby = fminf(fmaxf(fy + 1.f, 0.f), 97.f);
    float pxc = fminf(fmaxf(px, 0.f), 97.f);
    float pyc = fminf(fmaxf(py, 0.f), 97.f);
    float glt = (1.f + (qltx - pxc)) * (1.f + (qlty - pyc));
    float grb = (1.f - (qrbx - pxc)) * (1.f - (qrby - pyc));
    float glb = (1.f + (qltx - pxc)) * (1.f - (qrby - pyc));
    float grt = (1.f - (qrbx - pxc)) * (1.f + (qlty - pyc));
    int x0 = (int)qltx - 1, y0 = (int)qlty - 1;
    int x1 = (int)qrbx - 1, y1 = (int)qrby - 1;
    bool vlt = (x0 >= 0 && x0 < 96 && y0 >= 0 && y0 < 96);
    bool vrb = (x1 >= 0 && x1 < 96 && y1 >= 0 && y1 < 96);
    bool vlb = (x0 >= 0 && x0 < 96 && y1 >= 0 && y1 < 96);
    bool vrt = (x1 >= 0 && x1 < 96 && y0 >= 0 && y0 < 96);
    int4 id;
    id.x = vlt ? x0 * 96 + y0 : 0;
    id.y = vrb ? x1 * 96 + y1 : 0;
    id.z = vlb ? x0 * 96 + y1 : 0;
    id.w = vrt ? x1 * 96 + y0 : 0;
    idx4[idx] = id;
    wgt4[idx] = make_float4(vlt ? glt : 0.f, vrb ? grb : 0.f,
                            vlb ? glb : 0.f, vrt ? grt : 0.f);
}

// ---- deformable conv MFMA: BN=32, grid 1152, T14 pipeline + T5 (proven R8) ----
__global__ __launch_bounds__(256) void k_dconv(const float* __restrict__ x,
                                               const ushort* __restrict__ wt2h,
                                               const ushort* __restrict__ wt2l,
                                               const int4* __restrict__ idx4,
                                               const float4* __restrict__ wgt4,
                                               float* __restrict__ qpart) {
    int s = blockIdx.x;
    int xcd = s & 7, ib = s >> 3;
    int combo = xcd >> 1;
    int b = combo & 1;
    int half = combo >> 1;
    int ptile = (xcd & 1) * 144 + ib;
    int p0 = ptile * 32;
    int t = threadIdx.x;
    int l = t & 63, w = t >> 6;
    int lrow = l & 15, lhi = l >> 4;
    int obase = w * 64;
    int pl = t & 31, cg = t >> 5;

    __shared__ __align__(16) ushort Sh0[32 * 40], Sl0[32 * 40];
    __shared__ __align__(16) ushort Sh1[32 * 40], Sl1[32 * 40];
    __shared__ int4 Tid[9 * 32];
    __shared__ float4 Twg[9 * 32];

    for (int e = t; e < 9 * 32; e += 256) {
        int kk = e >> 5, pq = e & 31;
        size_t tb = ((size_t)b * 9 + kk) * PP + p0 + pq;
        Tid[e] = idx4[tb];
        Twg[e] = wgt4[tb];
    }

    f32x4 acc[4][2];
#pragma unroll
    for (int mf = 0; mf < 4; ++mf)
#pragma unroll
        for (int nf = 0; nf < 2; ++nf) acc[mf][nf] = (f32x4)0.f;

    const float* xb = x + (size_t)b * CC * PP;
    int h4 = half * 4;

    float R[16];
    float4 g4r;

    auto LD = [&](int i) {
        int cs = i / 9, kk = i % 9;
        int csg = h4 + cs;
        int4 id = Tid[kk * 32 + pl];
        g4r = Twg[kk * 32 + pl];
        const float* xp0 = xb + (size_t)(csg * 32 + cg * 4) * PP;
#pragma unroll
        for (int q = 0; q < 4; ++q) {
            const float* xc = xp0 + (size_t)q * PP;
            R[q * 4 + 0] = xc[id.x];
            R[q * 4 + 1] = xc[id.y];
            R[q * 4 + 2] = xc[id.z];
            R[q * 4 + 3] = xc[id.w];
        }
    };
    auto CONV = [&](ushort* Sh, ushort* Sl) {
        ushort4 vh, vl;
#pragma unroll
        for (int q = 0; q < 4; ++q) {
            float v = g4r.x * R[q * 4 + 0];
            v = fmaf(g4r.y, R[q * 4 + 1], v);
            v = fmaf(g4r.z, R[q * 4 + 2], v);
            v = fmaf(g4r.w, R[q * 4 + 3], v);
            ushort hh = f2bf_rne(v);
            ushort ll = f2bf_rne(v - bf2f(hh));
            if (q == 0)      { vh.x = hh; vl.x = ll; }
            else if (q == 1) { vh.y = hh; vl.y = ll; }
            else if (q == 2) { vh.z = hh; vl.z = ll; }
            else             { vh.w = hh; vl.w = ll; }
        }
        *(ushort4*)&Sh[pl * 40 + cg * 4] = vh;
        *(ushort4*)&Sl[pl * 40 + cg * 4] = vl;
    };
    auto COMPUTE = [&](int i, const ushort* Sh, const ushort* Sl) {
        int cs = i / 9, kk = i % 9;
        int csg = h4 + cs;
        bf16x8 ah[4], al[4];
#pragma unroll
        for (int mf = 0; mf < 4; ++mf) {
            size_t gi = (((size_t)(kk * 8 + csg)) * 1024 + ((w * 4 + mf) * 64 + l)) * 8;
            ah[mf] = *(const bf16x8*)&wt2h[gi];
            al[mf] = *(const bf16x8*)&wt2l[gi];
        }
        bf16x8 Bh2[2], Bl2[2];
#pragma unroll
        for (int nf = 0; nf < 2; ++nf) {
            Bh2[nf] = *(const bf16x8*)&Sh[(nf * 16 + lrow) * 40 + lhi * 8];
            Bl2[nf] = *(const bf16x8*)&Sl[(nf * 16 + lrow) * 40 + lhi * 8];
        }
        __builtin_amdgcn_s_setprio(1);
#pragma unroll
        for (int mf = 0; mf < 4; ++mf)
#pragma unroll
            for (int nf = 0; nf < 2; ++nf) {
                acc[mf][nf] = __builtin_amdgcn_mfma_f32_16x16x32_bf16(ah[mf], Bh2[nf], acc[mf][nf], 0, 0, 0);
                acc[mf][nf] = __builtin_amdgcn_mfma_f32_16x16x32_bf16(ah[mf], Bl2[nf], acc[mf][nf], 0, 0, 0);
                acc[mf][nf] = __builtin_amdgcn_mfma_f32_16x16x32_bf16(al[mf], Bh2[nf], acc[mf][nf], 0, 0, 0);
            }
        __builtin_amdgcn_s_setprio(0);
    };

    __syncthreads();
    LD(0); CONV(Sh0, Sl0);
    LD(1);
    __syncthreads();

#pragma unroll 1
    for (int i0 = 0; i0 < 36; i0 += 2) {
        CONV(Sh1, Sl1);
        if (i0 + 2 < 36) LD(i0 + 2);
        COMPUTE(i0, Sh0, Sl0);
        __syncthreads();
        if (i0 + 2 < 36) CONV(Sh0, Sl0);
        if (i0 + 3 < 36) LD(i0 + 3);
        COMPUTE(i0 + 1, Sh1, Sl1);
        __syncthreads();
    }

    float* qh = qpart + (size_t)half * BB * CC * PP + (size_t)b * CC * PP;
#pragma unroll
    for (int mf = 0; mf < 4; ++mf)
#pragma unroll
        for (int nf = 0; nf < 2; ++nf)
#pragma unroll
            for (int j = 0; j < 4; ++j)
                qh[(size_t)(obase + mf * 16 + lhi * 4 + j) * PP + p0 + nf * 16 + lrow] =
                    acc[mf][nf][j];
}

// ---- generic MFMA GEMM; B from fp32 (convert in-kernel) ----
__global__ __launch_bounds__(256) void k_gemm_bf(const float* __restrict__ Bsrc,
                                                 const ushort* __restrict__ A2h,
                                                 const ushort* __restrict__ A2l,
                                                 float* __restrict__ C,
                                                 int mtiles, int bRowStride, int bRowOff,
                                                 int aBatchStride,
                                                 float* __restrict__ npart) {
    int s = blockIdx.x;
    int xcd = s & 7, ib = s >> 3;
    int b, mt, ptile;
    if (mtiles == 2) {
        int combo = xcd >> 1;
        b = combo & 1; mt = combo >> 1;
        ptile = (xcd & 1) * 72 + ib;
    } else {
        b = xcd >> 2; mt = 0;
        ptile = (xcd & 3) * 36 + ib;
    }
    int p0 = ptile * 64;
    int t = threadIdx.x;
    int l = t & 63, w = t >> 6;
    int lrow = l & 15, lhi = l >> 4;
    int obase = w * 64;
    int p = t & 63, cg = t >> 6;
    __shared__ __align__(16) ushort Sh[64 * 40];
    __shared__ __align__(16) ushort Sl[64 * 40];
    f32x4 acc[4][4];
#pragma unroll
    for (int mf = 0; mf < 4; ++mf)
#pragma unroll
        for (int nf = 0; nf < 4; ++nf) acc[mf][nf] = (f32x4)0.f;
    const float* Bb = Bsrc + ((size_t)b * bRowStride + bRowOff) * PP;
    const ushort* Ah = A2h + (size_t)b * aBatchStride;
    const ushort* Al = A2l + (size_t)b * aBatchStride;
#pragma unroll 1
    for (int csg = 0; csg < 8; ++csg) {
        __syncthreads();
        bf16x8 ah[4], al[4];
#pragma unroll
        for (int mf = 0; mf < 4; ++mf) {
            size_t gi = (((size_t)(mt * 8 + csg)) * 1024 + ((w * 4 + mf) * 64 + l)) * 8;
            ah[mf] = *(const bf16x8*)&Ah[gi];
            al[mf] = *(const bf16x8*)&Al[gi];
        }
        const float* xr = Bb + (size_t)(csg * 32 + cg * 8) * PP + p0 + p;
        bf16x8 vh, vl;
#pragma unroll
        for (int i = 0; i < 8; ++i) {
            float v = xr[(size_t)i * PP];
            ushort hh = f2bf_rne(v);
            vh[i] = (short)hh;
            vl[i] = (short)f2bf_rne(v - bf2f(hh));
        }
        *(bf16x8*)&Sh[p * 40 + cg * 8] = vh;
        *(bf16x8*)&Sl[p * 40 + cg * 8] = vl;
        __syncthreads();
        bf16x8 Bh4[4], Bl4[4];
#pragma unroll
        for (int nf = 0; nf < 4; ++nf) {
            Bh4[nf] = *(const bf16x8*)&Sh[(nf * 16 + lrow) * 40 + lhi * 8];
            Bl4[nf] = *(const bf16x8*)&Sl[(nf * 16 + lrow) * 40 + lhi * 8];
        }
#pragma unroll
        for (int mf = 0; mf < 4; ++mf) {
#pragma unroll
            for (int nf = 0; nf < 4; ++nf) {
                acc[mf][nf] = __builtin_amdgcn_mfma_f32_16x16x32_bf16(ah[mf], Bh4[nf], acc[mf][nf], 0, 0, 0);
                acc[mf][nf] = __builtin_amdgcn_mfma_f32_16x16x32_bf16(ah[mf], Bl4[nf], acc[mf][nf], 0, 0, 0);
                acc[mf][nf] = __builtin_amdgcn_mfma_f32_16x16x32_bf16(al[mf], Bh4[nf], acc[mf][nf], 0, 0, 0);
            }
        }
    }
    float* Cb = C + (size_t)b * (mtiles * 256) * PP;
#pragma unroll
    for (int mf = 0; mf < 4; ++mf)
#pragma unroll
        for (int nf = 0; nf < 4; ++nf)
#pragma unroll
            for (int j = 0; j < 4; ++j)
                Cb[(size_t)(mt * 256 + obase + mf * 16 + lhi * 4 + j) * PP + p0 + nf * 16 + lrow] =
                    acc[mf][nf][j];
    if (npart) {
        float sq[4][4];
#pragma unroll
        for (int mf = 0; mf < 4; ++mf)
#pragma unroll
            for (int j = 0; j < 4; ++j) {
                float v0 = acc[mf][0][j], v1 = acc[mf][1][j];
                float v2 = acc[mf][2][j], v3 = acc[mf][3][j];
                sq[mf][j] = v0 * v0 + v1 * v1 + v2 * v2 + v3 * v3;
            }
#pragma unroll
        for (int m = 1; m <= 8; m <<= 1)
#pragma unroll
            for (int mf = 0; mf < 4; ++mf)
#pragma unroll
                for (int j = 0; j < 4; ++j)
                    sq[mf][j] += __shfl_xor(sq[mf][j], m, 64);
        if (lrow == 0) {
            float* np = npart + ((size_t)(b * 2 + mt) * 144 + ptile) * 256;
#pragma unroll
            for (int mf = 0; mf < 4; ++mf)
#pragma unroll
                for (int j = 0; j < 4; ++j)
                    np[obase + mf * 16 + lhi * 4 + j] = sq[mf][j];
        }
    }
}

// ---- attention score partials: q . k over 512-p chunks (NCH=18) ----
__global__ __launch_bounds__(256) void k_attn_part(const float* __restrict__ qp,
                                                   const float* __restrict__ kv,
                                                   float* __restrict__ apart) {
    int ch = blockIdx.x, h = blockIdx.y, b = blockIdx.z;
    int t = threadIdx.x;
    int d = t & 31, cg = t >> 5;
    __shared__ float qs[32][37], ks[32][37];
    float acc[4] = {0.f, 0.f, 0.f, 0.f};
    const float* q0 = qp + ((size_t)b * CC + h * 32) * PP;
    const float* q1 = q0 + (size_t)BB * CC * PP;
    const float* kb = kv + ((size_t)b * 512 + h * 32) * PP;
    int r = t >> 3, cq = (t & 7) * 4;
    for (int po = ch * 512; po < ch * 512 + 512; po += 32) {
        float4 va = *(const float4*)&q0[(size_t)r * PP + po + cq];
        float4 vb = *(const float4*)&q1[(size_t)r * PP + po + cq];
        qs[r][cq + 0] = va.x + vb.x; qs[r][cq + 1] = va.y + vb.y;
        qs[r][cq + 2] = va.z + vb.z; qs[r][cq + 3] = va.w + vb.w;
        float4 vk = *(const float4*)&kb[(size_t)r * PP + po + cq];
        ks[r][cq + 0] = vk.x; ks[r][cq + 1] = vk.y;
        ks[r][cq + 2] = vk.z; ks[r][cq + 3] = vk.w;
        __syncthreads();
#pragma unroll
        for (int pq = 0; pq < 32; ++pq) {
            float kvv = ks[d][pq];
#pragma unroll
            for (int i = 0; i < 4; ++i)
                acc[i] = fmaf(qs[cg * 4 + i][pq], kvv, acc[i]);
        }
        __syncthreads();
    }
    float* ap = apart + (((size_t)(b * 8 + h) * NCH + ch) << 10);
#pragma unroll
    for (int i = 0; i < 4; ++i) ap[(cg * 4 + i) * 32 + d] = acc[i];
}

// ---- merged: norms + reduce + softmax + W2 = Wproj-slice @ As ----
__global__ __launch_bounds__(256) void k_attn_fin_w2(const float* __restrict__ apart,
                                                     const float* __restrict__ npart,
                                                     const float* __restrict__ temp,
                                                     const float* __restrict__ wproj,
                                                     ushort* __restrict__ w2h,
                                                     ushort* __restrict__ w2l) {
    int h = blockIdx.x, b = blockIdx.y;
    int t = threadIdx.x;
    __shared__ float A[32][33];
    __shared__ float invk[32], invv[32];
    if (t < 64) {
        int mt = t >> 5, row = (t & 31) + h * 32;
        const float* base = npart + ((size_t)(b * 2 + mt) * 144) * 256 + row;
        float ssum = 0.f;
        for (int pt = 0; pt < 144; ++pt) ssum += base[pt * 256];
        float iv = 1.f / fmaxf(sqrtf(ssum), 1e-12f);
        if (mt == 0) invk[t & 31] = iv; else invv[t & 31] = iv;
    }
    const float* ap = apart + ((size_t)(b * 8 + h) * NCH << 10);
    float th = temp[h];
    for (int e = t; e < 1024; e += 256) {
        float s = 0.f;
        for (int chn = 0; chn < NCH; ++chn) s += ap[chn * 1024 + e];
        A[e >> 5][e & 31] = s * th;
    }
    __syncthreads();
    if (t < 32) {
        int c = t;
        float m = -INFINITY;
        float row[32];
#pragma unroll
        for (int d = 0; d < 32; ++d) {
            row[d] = A[c][d] * invk[d];
            m = fmaxf(m, row[d]);
        }
        float sum = 0.f;
#pragma unroll
        for (int d = 0; d < 32; ++d) sum += expf(row[d] - m);
        float inv = 1.f / sum;
#pragma unroll
        for (int d = 0; d < 32; ++d)
            A[c][d] = expf(row[d] - m) * inv * invv[d];
    }
    __syncthreads();
    int o = t;
    float wrow[32];
#pragma unroll
    for (int c = 0; c < 32; ++c) wrow[c] = wproj[o * 256 + h * 32 + c];
    int wq = o >> 6, mf = (o >> 4) & 3, lr = o & 15;
    size_t bb = (size_t)b * 65536;
#pragma unroll
    for (int e = 0; e < 32; ++e) {
        float v = 0.f;
#pragma unroll
        for (int c = 0; c < 32; ++c) v = fmaf(wrow[c], A[c][e], v);
        int lhi = e >> 3, ee = e & 7;
        size_t gi = bb + ((size_t)h * 1024 + ((wq * 4 + mf) * 64 + lhi * 16 + lr)) * 8 + ee;
        ushort hh = f2bf_rne(v);
        w2h[gi] = hh;
        w2l[gi] = f2bf_rne(v - bf2f(hh));
    }
}

extern "C" void kernel_launch(void* const* d_in, const int* in_sizes, int n_in,
                              void* d_out, int out_size, void* d_ws, size_t ws_size,
                              hipStream_t stream) {
    const float* x     = (const float*)d_in[0];
    const float* wp    = (const float*)d_in[1];
    const float* bp    = (const float*)d_in[2];
    const float* wd    = (const float*)d_in[3];
    const float* wqkv  = (const float*)d_in[4];
    const float* temp  = (const float*)d_in[5];
    const float* wproj = (const float*)d_in[6];
    float* out = (float*)d_out;
    float* ws  = (float*)d_ws;

    float* npart  = ws + NP_O;
    ushort* w2h   = (ushort*)(ws + W2_O);
    ushort* w2l   = w2h + 2 * 65536;
    int4*  idx4   = (int4*)(ws + IDX_O);
    float4* wgt4  = (float4*)(ws + WGT_O);
    ushort* wt2h  = (ushort*)(ws + WT2_O);
    ushort* wt2l  = wt2h + 9 * 8 * 1024 * 8;
    ushort* wp2h  = (ushort*)(ws + WP2_O);
    ushort* wp2l  = wp2h + 9 * 8 * 128 * 8;
    ushort* wq2h  = (ushort*)(ws + WQ2_O);
    ushort* wq2l  = wq2h + 2 * 8 * 1024 * 8;
    float* qpart  = ws + QP_O;   // aliases ppart (sequential lifetimes)
    float* ppart  = ws + QP_O;
    float* kv     = ws + KV_O;
    float* apart  = ws + AP_O;

    k_prep_wt<<<2304, 256, 0, stream>>>(wd, wt2h, wt2l);
    k_prep_wp<<<288, 256, 0, stream>>>(wp, wp2h, wp2l);
    k_prep_w<<<512, 256, 0, stream>>>(wqkv + 256 * 256, wq2h, wq2l, 2 * 65536);
    k_pconv<<<1152, 256, 0, stream>>>(x, wp2h, wp2l, ppart);
    k_bilin2<<<(BB * 9 * PP + 255) / 256, 256, 0, stream>>>(ppart, bp, idx4, wgt4);
    k_dconv<<<1152, 256, 0, stream>>>(x, wt2h, wt2l, idx4, wgt4, qpart);
    k_gemm_bf<<<576, 256, 0, stream>>>(x, wq2h, wq2l, kv, 2, 256, 0, 0, npart);
    k_attn_part<<<dim3(NCH, HEADS, BB), 256, 0, stream>>>(qpart, kv, apart);
    k_attn_fin_w2<<<dim3(HEADS, BB), 256, 0, stream>>>(apart, npart, temp, wproj, w2h, w2l);
    k_gemm_bf<<<288, 256, 0, stream>>>(kv, w2h, w2l, out, 1, 512, 256, 65536, nullptr);
}

// Round 14
// 267.261 us; speedup vs baseline: 3.2229x; 1.1245x over previous
//
#include <hip/hip_runtime.h>
#include <math.h>

#define BB 2
#define CC 256
#define HW 96
#define PP 9216
#define KO 18
#define HEADS 8
#define NCH 18

typedef short bf16x8 __attribute__((ext_vector_type(8)));
typedef float f32x4 __attribute__((ext_vector_type(4)));

// ws layout (float offsets), lifetime-aliased
#define NP_O    0UL          // norm partials 4*144*256 = 147456
#define W2_O    147456UL     // W2 hi+lo (2 batches) = 131072 -> ends 278528
#define IDX_O   331776UL     // int4 table 663552 (dead after dconv)
#define WGT_O   995328UL     // float4 table 663552 (dead after dconv)
#define WT2_O   1658880UL    // wt2 hi+lo = 589824 (dead after dconv)
#define WP2_O   2248704UL    // wp2 hi+lo = 73728 (dead after pconv)
#define WQ2_O   2322432UL    // wq2 hi+lo = 131072 (dead after qkv)
#define QP_O    2584576UL    // qpart 9437184 (aliases ppart; dead after attn_part)
#define KV_O    12021760UL   // xT (4718592, lives k_xt..dconv) then k,v fp32 (9437184)
#define AP_O    21459968UL   // attn partials 2*8*18*1024 = 294912

__device__ __forceinline__ ushort f2bf_rne(float f) {
    unsigned u = __float_as_uint(f);
    unsigned r = (u + 0x7FFFu + ((u >> 16) & 1u)) >> 16;
    return (ushort)r;
}
__device__ __forceinline__ float bf2f(ushort h) {
    return __uint_as_float(((unsigned)h) << 16);
}

// ---- prep: wd[o][c][kk] -> wt2 hi/lo [kk][csg][(oh*64 + lhi*16 + lrow)]*8 ----
__global__ __launch_bounds__(256) void k_prep_wt(const float* __restrict__ wd,
                                                 ushort* __restrict__ h,
                                                 ushort* __restrict__ lo) {
    int tid = blockIdx.x * 256 + threadIdx.x;
    if (tid >= 9 * 8 * 1024 * 8) return;
    int e = tid & 7;
    int u = (tid >> 3) & 1023;
    int cs = (tid >> 13) & 7;
    int kk = tid >> 16;
    int oh = u >> 6, rem = u & 63;
    int lrow = rem & 15, lhi = rem >> 4;
    int o = oh * 16 + lrow;
    int c = cs * 32 + lhi * 8 + e;
    float v = wd[o * 2304 + c * 9 + kk];
    ushort hh = f2bf_rne(v);
    h[tid] = hh;
    lo[tid] = f2bf_rne(v - bf2f(hh));
}

// ---- prep: wp (o<18, pad to 32) -> wp2 hi/lo, identity lane layout ----
__global__ __launch_bounds__(256) void k_prep_wp(const float* __restrict__ wp,
                                                 ushort* __restrict__ h,
                                                 ushort* __restrict__ lo) {
    int tid = blockIdx.x * 256 + threadIdx.x;
    if (tid >= 9 * 8 * 128 * 8) return;
    int e = tid & 7;
    int u = (tid >> 3) & 127;
    int cs = (tid >> 10) & 7;
    int kk = tid >> 13;
    int mf = u >> 6, rem = u & 63;
    int lrow = rem & 15, lhi = rem >> 4;
    int o = mf * 16 + lrow;
    int c = cs * 32 + lhi * 8 + e;
    float v = (o < KO) ? wp[(o * 256 + c) * 9 + kk] : 0.f;
    ushort hh = f2bf_rne(v);
    h[tid] = hh;
    lo[tid] = f2bf_rne(v - bf2f(hh));
}

// ---- prep generic weight W[M][256] -> [mt][csg][u]*8 hi/lo, identity lane layout ----
__global__ __launch_bounds__(256) void k_prep_w(const float* __restrict__ W,
                                                ushort* __restrict__ h,
                                                ushort* __restrict__ lo,
                                                int total) {
    int tid = blockIdx.x * 256 + threadIdx.x;
    if (tid >= total) return;
    int e = tid & 7;
    int u = (tid >> 3) & 1023;
    int csg = (tid >> 13) & 7;
    int mt = tid >> 16;
    int rem = u & 63;
    int lrow = rem & 15, lhi = rem >> 4;
    int o = mt * 256 + (u >> 6) * 16 + lrow;
    int c = csg * 32 + lhi * 8 + e;
    float v = W[o * 256 + c];
    ushort hh = f2bf_rne(v);
    h[tid] = hh;
    lo[tid] = f2bf_rne(v - bf2f(hh));
}

// ---- x[b][c][p] -> xT[b][p][c] (LDS-tiled 64x64 transpose) ----
__global__ __launch_bounds__(256) void k_xt(const float* __restrict__ x,
                                            float* __restrict__ xT) {
    int pt = blockIdx.x;   // 144 tiles of 64 pixels
    int ct = blockIdx.y;   // 4 tiles of 64 channels
    int b  = blockIdx.z;
    int t = threadIdx.x;
    __shared__ float T[64][65];
    {
        int c = t >> 2, pq = (t & 3) * 16;
        const float* src = x + ((size_t)b * CC + ct * 64 + c) * PP + pt * 64 + pq;
#pragma unroll
        for (int k2 = 0; k2 < 4; ++k2) {
            float4 v = *(const float4*)&src[k2 * 4];
            T[c][pq + k2 * 4 + 0] = v.x;
            T[c][pq + k2 * 4 + 1] = v.y;
            T[c][pq + k2 * 4 + 2] = v.z;
            T[c][pq + k2 * 4 + 3] = v.w;
        }
    }
    __syncthreads();
    {
        int p = t >> 2, cq = (t & 3) * 16;
        float* dst = xT + ((size_t)b * PP + pt * 64 + p) * CC + ct * 64 + cq;
#pragma unroll
        for (int k2 = 0; k2 < 4; ++k2)
            *(float4*)&dst[k2 * 4] = make_float4(T[cq + k2 * 4 + 0][p], T[cq + k2 * 4 + 1][p],
                                                 T[cq + k2 * 4 + 2][p], T[cq + k2 * 4 + 3][p]);
    }
}

// ---- pconv MFMA, XCD-swizzled 1D grid of 1152 ----
__global__ __launch_bounds__(256) void k_pconv(const float* __restrict__ x,
                                               const ushort* __restrict__ wp2h,
                                               const ushort* __restrict__ wp2l,
                                               float* __restrict__ ppart) {
    int s = blockIdx.x;
    int xcd = s & 7;
    int b = xcd & 1, ks = xcd >> 1;
    int p0 = (s >> 3) * 64;
    int t = threadIdx.x;
    int l = t & 63, w = t >> 6;
    int lrow = l & 15, lhi = l >> 4;
    int p = t & 63, cg = t >> 6;
    __shared__ __align__(16) ushort Sh[64 * 40];
    __shared__ __align__(16) ushort Sl[64 * 40];
    f32x4 acc[2];
    acc[0] = (f32x4)0.f; acc[1] = (f32x4)0.f;
    const float* xb = x + (size_t)b * CC * PP;
    int pix = p0 + p;
    int i_ = pix / 96, j_ = pix % 96;
#pragma unroll 1
    for (int cs = 0; cs < 2; ++cs) {
        int csg = ks * 2 + cs;
        const float* xc0 = xb + (size_t)(csg * 32 + cg * 8) * PP;
#pragma unroll 1
        for (int kk = 0; kk < 9; ++kk) {
            int di = kk / 3 - 1, dj = kk % 3 - 1;
            bool vOK = ((unsigned)(i_ + di) < 96u) && ((unsigned)(j_ + dj) < 96u);
            int poff = pix + di * 96 + dj;
            __syncthreads();
            bf16x8 ah[2], al[2];
#pragma unroll
            for (int mf = 0; mf < 2; ++mf) {
                size_t gi = (((size_t)(kk * 8 + csg)) * 128 + (mf * 64 + l)) * 8;
                ah[mf] = *(const bf16x8*)&wp2h[gi];
                al[mf] = *(const bf16x8*)&wp2l[gi];
            }
            bf16x8 vh, vl;
#pragma unroll
            for (int i = 0; i < 8; ++i) {
                float v = vOK ? xc0[(size_t)i * PP + poff] : 0.f;
                ushort hh = f2bf_rne(v);
                vh[i] = (short)hh;
                vl[i] = (short)f2bf_rne(v - bf2f(hh));
            }
            *(bf16x8*)&Sh[p * 40 + cg * 8] = vh;
            *(bf16x8*)&Sl[p * 40 + cg * 8] = vl;
            __syncthreads();
            bf16x8 Bh = *(const bf16x8*)&Sh[(w * 16 + lrow) * 40 + lhi * 8];
            bf16x8 Bl = *(const bf16x8*)&Sl[(w * 16 + lrow) * 40 + lhi * 8];
#pragma unroll
            for (int mf = 0; mf < 2; ++mf) {
                acc[mf] = __builtin_amdgcn_mfma_f32_16x16x32_bf16(ah[mf], Bh, acc[mf], 0, 0, 0);
                acc[mf] = __builtin_amdgcn_mfma_f32_16x16x32_bf16(ah[mf], Bl, acc[mf], 0, 0, 0);
                acc[mf] = __builtin_amdgcn_mfma_f32_16x16x32_bf16(al[mf], Bh, acc[mf], 0, 0, 0);
            }
        }
    }
    float* pr = ppart + ((size_t)(ks * BB + b) * 32) * PP;
#pragma unroll
    for (int mf = 0; mf < 2; ++mf)
#pragma unroll
        for (int j = 0; j < 4; ++j)
            pr[(size_t)(mf * 16 + lhi * 4 + j) * PP + p0 + w * 16 + lrow] = acc[mf][j];
}

// ---- bilinear table (fused partial-reduce + bias + bilin math) ----
__global__ __launch_bounds__(256) void k_bilin2(const float* __restrict__ pp,
                                                const float* __restrict__ bp,
                                                int4* __restrict__ idx4,
                                                float4* __restrict__ wgt4) {
    int idx = blockIdx.x * 256 + threadIdx.x;
    if (idx >= BB * 9 * PP) return;
    int p = idx % PP;
    int bn = idx / PP;
    int n = bn % 9, b = bn / 9;
    int i = p / 96, j = p % 96;
    float ox = bp[n], oy = bp[n + 9];
#pragma unroll
    for (int k = 0; k < 4; ++k) {
        ox += pp[((size_t)(k * BB + b) * 32 + n) * PP + p];
        oy += pp[((size_t)(k * BB + b) * 32 + n + 9) * PP + p];
    }
    float px = ox + (float)(n / 3 - 1) + (float)(i + 1);
    float py = oy + (float)(n % 3 - 1) + (float)(j + 1);
    float fx = floorf(px), fy = floorf(py);
    float qltx = fminf(fmaxf(fx, 0.f), 97.f);
    float qlty = fminf(fmaxf(fy, 0.f), 97.f);
    float qrbx = fminf(fmaxf(fx + 1.f, 0.f), 97.f);
    float qrby = fminf(fmaxf(fy + 1.f, 0.f), 97.f);
    float pxc = fminf(fmaxf(px, 0.f), 97.f);
    float pyc = fminf(fmaxf(py, 0.f), 97.f);
    float glt = (1.f + (qltx - pxc)) * (1.f + (qlty - pyc));
    float grb = (1.f - (qrbx - pxc)) * (1.f - (qrby - pyc));
    float glb = (1.f + (qltx - pxc)) * (1.f - (qrby - pyc));
    float grt = (1.f - (qrbx - pxc)) * (1.f + (qlty - pyc));
    int x0 = (int)qltx - 1, y0 = (int)qlty - 1;
    int x1 = (int)qrbx - 1, y1 = (int)qrby - 1;
    bool vlt = (x0 >= 0 && x0 < 96 && y0 >= 0 && y0 < 96);
    bool vrb = (x1 >= 0 && x1 < 96 && y1 >= 0 && y1 < 96);
    bool vlb = (x0 >= 0 && x0 < 96 && y1 >= 0 && y1 < 96);
    bool vrt = (x1 >= 0 && x1 < 96 && y0 >= 0 && y0 < 96);
    int4 id;
    id.x = vlt ? x0 * 96 + y0 : 0;
    id.y = vrb ? x1 * 96 + y1 : 0;
    id.z = vlb ? x0 * 96 + y1 : 0;
    id.w = vrt ? x1 * 96 + y0 : 0;
    idx4[idx] = id;
    wgt4[idx] = make_float4(vlt ? glt : 0.f, vrb ? grb : 0.f,
                            vlb ? glb : 0.f, vrt ? grt : 0.f);
}

// ---- deformable conv MFMA: R8 schedule, gathers as float4 from xT[b][p][c] ----
__global__ __launch_bounds__(256) void k_dconv(const float* __restrict__ xT,
                                               const ushort* __restrict__ wt2h,
                                               const ushort* __restrict__ wt2l,
                                               const int4* __restrict__ idx4,
                                               const float4* __restrict__ wgt4,
                                               float* __restrict__ qpart) {
    int s = blockIdx.x;
    int xcd = s & 7, ib = s >> 3;
    int combo = xcd >> 1;
    int b = combo & 1;
    int half = combo >> 1;
    int ptile = (xcd & 1) * 144 + ib;
    int p0 = ptile * 32;
    int t = threadIdx.x;
    int l = t & 63, w = t >> 6;
    int lrow = l & 15, lhi = l >> 4;
    int obase = w * 64;
    int pl = t & 31, cg = t >> 5;

    __shared__ __align__(16) ushort Sh0[32 * 40], Sl0[32 * 40];
    __shared__ __align__(16) ushort Sh1[32 * 40], Sl1[32 * 40];
    __shared__ int4 Tid[9 * 32];
    __shared__ float4 Twg[9 * 32];

    for (int e = t; e < 9 * 32; e += 256) {
        int kk = e >> 5, pq = e & 31;
        size_t tb = ((size_t)b * 9 + kk) * PP + p0 + pq;
        Tid[e] = idx4[tb];
        Twg[e] = wgt4[tb];
    }

    f32x4 acc[4][2];
#pragma unroll
    for (int mf = 0; mf < 4; ++mf)
#pragma unroll
        for (int nf = 0; nf < 2; ++nf) acc[mf][nf] = (f32x4)0.f;

    const float* xTb = xT + (size_t)b * PP * CC;
    int h4 = half * 4;

    float R[16];          // R[corner*4 + c]
    float4 g4r;

    auto LD = [&](int i) {
        int cs = i / 9, kk = i % 9;
        int csg = h4 + cs;
        int4 id = Tid[kk * 32 + pl];
        g4r = Twg[kk * 32 + pl];
        const float* xt0 = xTb + (size_t)(csg * 32 + cg * 4);
        *(float4*)&R[0]  = *(const float4*)&xt0[(size_t)id.x * CC];
        *(float4*)&R[4]  = *(const float4*)&xt0[(size_t)id.y * CC];
        *(float4*)&R[8]  = *(const float4*)&xt0[(size_t)id.z * CC];
        *(float4*)&R[12] = *(const float4*)&xt0[(size_t)id.w * CC];
    };
    auto CONV = [&](ushort* Sh, ushort* Sl) {
        ushort4 vh, vl;
#pragma unroll
        for (int q = 0; q < 4; ++q) {
            float v = g4r.x * R[q];
            v = fmaf(g4r.y, R[4 + q], v);
            v = fmaf(g4r.z, R[8 + q], v);
            v = fmaf(g4r.w, R[12 + q], v);
            ushort hh = f2bf_rne(v);
            ushort ll = f2bf_rne(v - bf2f(hh));
            if (q == 0)      { vh.x = hh; vl.x = ll; }
            else if (q == 1) { vh.y = hh; vl.y = ll; }
            else if (q == 2) { vh.z = hh; vl.z = ll; }
            else             { vh.w = hh; vl.w = ll; }
        }
        *(ushort4*)&Sh[pl * 40 + cg * 4] = vh;
        *(ushort4*)&Sl[pl * 40 + cg * 4] = vl;
    };
    auto COMPUTE = [&](int i, const ushort* Sh, const ushort* Sl) {
        int cs = i / 9, kk = i % 9;
        int csg = h4 + cs;
        bf16x8 ah[4], al[4];
#pragma unroll
        for (int mf = 0; mf < 4; ++mf) {
            size_t gi = (((size_t)(kk * 8 + csg)) * 1024 + ((w * 4 + mf) * 64 + l)) * 8;
            ah[mf] = *(const bf16x8*)&wt2h[gi];
            al[mf] = *(const bf16x8*)&wt2l[gi];
        }
        bf16x8 Bh2[2], Bl2[2];
#pragma unroll
        for (int nf = 0; nf < 2; ++nf) {
            Bh2[nf] = *(const bf16x8*)&Sh[(nf * 16 + lrow) * 40 + lhi * 8];
            Bl2[nf] = *(const bf16x8*)&Sl[(nf * 16 + lrow) * 40 + lhi * 8];
        }
        __builtin_amdgcn_s_setprio(1);
#pragma unroll
        for (int mf = 0; mf < 4; ++mf)
#pragma unroll
            for (int nf = 0; nf < 2; ++nf) {
                acc[mf][nf] = __builtin_amdgcn_mfma_f32_16x16x32_bf16(ah[mf], Bh2[nf], acc[mf][nf], 0, 0, 0);
                acc[mf][nf] = __builtin_amdgcn_mfma_f32_16x16x32_bf16(ah[mf], Bl2[nf], acc[mf][nf], 0, 0, 0);
                acc[mf][nf] = __builtin_amdgcn_mfma_f32_16x16x32_bf16(al[mf], Bh2[nf], acc[mf][nf], 0, 0, 0);
            }
        __builtin_amdgcn_s_setprio(0);
    };

    __syncthreads();
    LD(0); CONV(Sh0, Sl0);
    LD(1);
    __syncthreads();

#pragma unroll 1
    for (int i0 = 0; i0 < 36; i0 += 2) {
        CONV(Sh1, Sl1);
        if (i0 + 2 < 36) LD(i0 + 2);
        COMPUTE(i0, Sh0, Sl0);
        __syncthreads();
        if (i0 + 2 < 36) CONV(Sh0, Sl0);
        if (i0 + 3 < 36) LD(i0 + 3);
        COMPUTE(i0 + 1, Sh1, Sl1);
        __syncthreads();
    }

    float* qh = qpart + (size_t)half * BB * CC * PP + (size_t)b * CC * PP;
#pragma unroll
    for (int mf = 0; mf < 4; ++mf)
#pragma unroll
        for (int nf = 0; nf < 2; ++nf)
#pragma unroll
            for (int j = 0; j < 4; ++j)
                qh[(size_t)(obase + mf * 16 + lhi * 4 + j) * PP + p0 + nf * 16 + lrow] =
                    acc[mf][nf][j];
}

// ---- generic MFMA GEMM; B from fp32 (convert in-kernel) ----
__global__ __launch_bounds__(256) void k_gemm_bf(const float* __restrict__ Bsrc,
                                                 const ushort* __restrict__ A2h,
                                                 const ushort* __restrict__ A2l,
                                                 float* __restrict__ C,
                                                 int mtiles, int bRowStride, int bRowOff,
                                                 int aBatchStride,
                                                 float* __restrict__ npart) {
    int s = blockIdx.x;
    int xcd = s & 7, ib = s >> 3;
    int b, mt, ptile;
    if (mtiles == 2) {
        int combo = xcd >> 1;
        b = combo & 1; mt = combo >> 1;
        ptile = (xcd & 1) * 72 + ib;
    } else {
        b = xcd >> 2; mt = 0;
        ptile = (xcd & 3) * 36 + ib;
    }
    int p0 = ptile * 64;
    int t = threadIdx.x;
    int l = t & 63, w = t >> 6;
    int lrow = l & 15, lhi = l >> 4;
    int obase = w * 64;
    int p = t & 63, cg = t >> 6;
    __shared__ __align__(16) ushort Sh[64 * 40];
    __shared__ __align__(16) ushort Sl[64 * 40];
    f32x4 acc[4][4];
#pragma unroll
    for (int mf = 0; mf < 4; ++mf)
#pragma unroll
        for (int nf = 0; nf < 4; ++nf) acc[mf][nf] = (f32x4)0.f;
    const float* Bb = Bsrc + ((size_t)b * bRowStride + bRowOff) * PP;
    const ushort* Ah = A2h + (size_t)b * aBatchStride;
    const ushort* Al = A2l + (size_t)b * aBatchStride;
#pragma unroll 1
    for (int csg = 0; csg < 8; ++csg) {
        __syncthreads();
        bf16x8 ah[4], al[4];
#pragma unroll
        for (int mf = 0; mf < 4; ++mf) {
            size_t gi = (((size_t)(mt * 8 + csg)) * 1024 + ((w * 4 + mf) * 64 + l)) * 8;
            ah[mf] = *(const bf16x8*)&Ah[gi];
            al[mf] = *(const bf16x8*)&Al[gi];
        }
        const float* xr = Bb + (size_t)(csg * 32 + cg * 8) * PP + p0 + p;
        bf16x8 vh, vl;
#pragma unroll
        for (int i = 0; i < 8; ++i) {
            float v = xr[(size_t)i * PP];
            ushort hh = f2bf_rne(v);
            vh[i] = (short)hh;
            vl[i] = (short)f2bf_rne(v - bf2f(hh));
        }
        *(bf16x8*)&Sh[p * 40 + cg * 8] = vh;
        *(bf16x8*)&Sl[p * 40 + cg * 8] = vl;
        __syncthreads();
        bf16x8 Bh4[4], Bl4[4];
#pragma unroll
        for (int nf = 0; nf < 4; ++nf) {
            Bh4[nf] = *(const bf16x8*)&Sh[(nf * 16 + lrow) * 40 + lhi * 8];
            Bl4[nf] = *(const bf16x8*)&Sl[(nf * 16 + lrow) * 40 + lhi * 8];
        }
#pragma unroll
        for (int mf = 0; mf < 4; ++mf) {
#pragma unroll
            for (int nf = 0; nf < 4; ++nf) {
                acc[mf][nf] = __builtin_amdgcn_mfma_f32_16x16x32_bf16(ah[mf], Bh4[nf], acc[mf][nf], 0, 0, 0);
                acc[mf][nf] = __builtin_amdgcn_mfma_f32_16x16x32_bf16(ah[mf], Bl4[nf], acc[mf][nf], 0, 0, 0);
                acc[mf][nf] = __builtin_amdgcn_mfma_f32_16x16x32_bf16(al[mf], Bh4[nf], acc[mf][nf], 0, 0, 0);
            }
        }
    }
    float* Cb = C + (size_t)b * (mtiles * 256) * PP;
#pragma unroll
    for (int mf = 0; mf < 4; ++mf)
#pragma unroll
        for (int nf = 0; nf < 4; ++nf)
#pragma unroll
            for (int j = 0; j < 4; ++j)
                Cb[(size_t)(mt * 256 + obase + mf * 16 + lhi * 4 + j) * PP + p0 + nf * 16 + lrow] =
                    acc[mf][nf][j];
    if (npart) {
        float sq[4][4];
#pragma unroll
        for (int mf = 0; mf < 4; ++mf)
#pragma unroll
            for (int j = 0; j < 4; ++j) {
                float v0 = acc[mf][0][j], v1 = acc[mf][1][j];
                float v2 = acc[mf][2][j], v3 = acc[mf][3][j];
                sq[mf][j] = v0 * v0 + v1 * v1 + v2 * v2 + v3 * v3;
            }
#pragma unroll
        for (int m = 1; m <= 8; m <<= 1)
#pragma unroll
            for (int mf = 0; mf < 4; ++mf)
#pragma unroll
                for (int j = 0; j < 4; ++j)
                    sq[mf][j] += __shfl_xor(sq[mf][j], m, 64);
        if (lrow == 0) {
            float* np = npart + ((size_t)(b * 2 + mt) * 144 + ptile) * 256;
#pragma unroll
            for (int mf = 0; mf < 4; ++mf)
#pragma unroll
                for (int j = 0; j < 4; ++j)
                    np[obase + mf * 16 + lhi * 4 + j] = sq[mf][j];
        }
    }
}

// ---- attention score partials: q . k over 512-p chunks (NCH=18) ----
__global__ __launch_bounds__(256) void k_attn_part(const float* __restrict__ qp,
                                                   const float* __restrict__ kv,
                                                   float* __restrict__ apart) {
    int ch = blockIdx.x, h = blockIdx.y, b = blockIdx.z;
    int t = threadIdx.x;
    int d = t & 31, cg = t >> 5;
    __shared__ float qs[32][37], ks[32][37];
    float acc[4] = {0.f, 0.f, 0.f, 0.f};
    const float* q0 = qp + ((size_t)b * CC + h * 32) * PP;
    const float* q1 = q0 + (size_t)BB * CC * PP;
    const float* kb = kv + ((size_t)b * 512 + h * 32) * PP;
    int r = t >> 3, cq = (t & 7) * 4;
    for (int po = ch * 512; po < ch * 512 + 512; po += 32) {
        float4 va = *(const float4*)&q0[(size_t)r * PP + po + cq];
        float4 vb = *(const float4*)&q1[(size_t)r * PP + po + cq];
        qs[r][cq + 0] = va.x + vb.x; qs[r][cq + 1] = va.y + vb.y;
        qs[r][cq + 2] = va.z + vb.z; qs[r][cq + 3] = va.w + vb.w;
        float4 vk = *(const float4*)&kb[(size_t)r * PP + po + cq];
        ks[r][cq + 0] = vk.x; ks[r][cq + 1] = vk.y;
        ks[r][cq + 2] = vk.z; ks[r][cq + 3] = vk.w;
        __syncthreads();
#pragma unroll
        for (int pq = 0; pq < 32; ++pq) {
            float kvv = ks[d][pq];
#pragma unroll
            for (int i = 0; i < 4; ++i)
                acc[i] = fmaf(qs[cg * 4 + i][pq], kvv, acc[i]);
        }
        __syncthreads();
    }
    float* ap = apart + (((size_t)(b * 8 + h) * NCH + ch) << 10);
#pragma unroll
    for (int i = 0; i < 4; ++i) ap[(cg * 4 + i) * 32 + d] = acc[i];
}

// ---- merged: norms + reduce + softmax + W2 = Wproj-slice @ As ----
__global__ __launch_bounds__(256) void k_attn_fin_w2(const float* __restrict__ apart,
                                                     const float* __restrict__ npart,
                                                     const float* __restrict__ temp,
                                                     const float* __restrict__ wproj,
                                                     ushort* __restrict__ w2h,
                                                     ushort* __restrict__ w2l) {
    int h = blockIdx.x, b = blockIdx.y;
    int t = threadIdx.x;
    __shared__ float A[32][33];
    __shared__ float invk[32], invv[32];
    if (t < 64) {
        int mt = t >> 5, row = (t & 31) + h * 32;
        const float* base = npart + ((size_t)(b * 2 + mt) * 144) * 256 + row;
        float ssum = 0.f;
        for (int pt = 0; pt < 144; ++pt) ssum += base[pt * 256];
        float iv = 1.f / fmaxf(sqrtf(ssum), 1e-12f);
        if (mt == 0) invk[t & 31] = iv; else invv[t & 31] = iv;
    }
    const float* ap = apart + ((size_t)(b * 8 + h) * NCH << 10);
    float th = temp[h];
    for (int e = t; e < 1024; e += 256) {
        float s = 0.f;
        for (int chn = 0; chn < NCH; ++chn) s += ap[chn * 1024 + e];
        A[e >> 5][e & 31] = s * th;
    }
    __syncthreads();
    if (t < 32) {
        int c = t;
        float m = -INFINITY;
        float row[32];
#pragma unroll
        for (int d = 0; d < 32; ++d) {
            row[d] = A[c][d] * invk[d];
            m = fmaxf(m, row[d]);
        }
        float sum = 0.f;
#pragma unroll
        for (int d = 0; d < 32; ++d) sum += expf(row[d] - m);
        float inv = 1.f / sum;
#pragma unroll
        for (int d = 0; d < 32; ++d)
            A[c][d] = expf(row[d] - m) * inv * invv[d];
    }
    __syncthreads();
    int o = t;
    float wrow[32];
#pragma unroll
    for (int c = 0; c < 32; ++c) wrow[c] = wproj[o * 256 + h * 32 + c];
    int wq = o >> 6, mf = (o >> 4) & 3, lr = o & 15;
    size_t bb = (size_t)b * 65536;
#pragma unroll
    for (int e = 0; e < 32; ++e) {
        float v = 0.f;
#pragma unroll
        for (int c = 0; c < 32; ++c) v = fmaf(wrow[c], A[c][e], v);
        int lhi = e >> 3, ee = e & 7;
        size_t gi = bb + ((size_t)h * 1024 + ((wq * 4 + mf) * 64 + lhi * 16 + lr)) * 8 + ee;
        ushort hh = f2bf_rne(v);
        w2h[gi] = hh;
        w2l[gi] = f2bf_rne(v - bf2f(hh));
    }
}

extern "C" void kernel_launch(void* const* d_in, const int* in_sizes, int n_in,
                              void* d_out, int out_size, void* d_ws, size_t ws_size,
                              hipStream_t stream) {
    const float* x     = (const float*)d_in[0];
    const float* wp    = (const float*)d_in[1];
    const float* bp    = (const float*)d_in[2];
    const float* wd    = (const float*)d_in[3];
    const float* wqkv  = (const float*)d_in[4];
    const float* temp  = (const float*)d_in[5];
    const float* wproj = (const float*)d_in[6];
    float* out = (float*)d_out;
    float* ws  = (float*)d_ws;

    float* npart  = ws + NP_O;
    ushort* w2h   = (ushort*)(ws + W2_O);
    ushort* w2l   = w2h + 2 * 65536;
    int4*  idx4   = (int4*)(ws + IDX_O);
    float4* wgt4  = (float4*)(ws + WGT_O);
    ushort* wt2h  = (ushort*)(ws + WT2_O);
    ushort* wt2l  = wt2h + 9 * 8 * 1024 * 8;
    ushort* wp2h  = (ushort*)(ws + WP2_O);
    ushort* wp2l  = wp2h + 9 * 8 * 128 * 8;
    ushort* wq2h  = (ushort*)(ws + WQ2_O);
    ushort* wq2l  = wq2h + 2 * 8 * 1024 * 8;
    float* qpart  = ws + QP_O;   // aliases ppart (sequential lifetimes)
    float* ppart  = ws + QP_O;
    float* xT     = ws + KV_O;   // lives [k_xt .. k_dconv]; kv overwrites after
    float* kv     = ws + KV_O;
    float* apart  = ws + AP_O;

    k_prep_wt<<<2304, 256, 0, stream>>>(wd, wt2h, wt2l);
    k_prep_wp<<<288, 256, 0, stream>>>(wp, wp2h, wp2l);
    k_prep_w<<<512, 256, 0, stream>>>(wqkv + 256 * 256, wq2h, wq2l, 2 * 65536);
    k_pconv<<<1152, 256, 0, stream>>>(x, wp2h, wp2l, ppart);
    k_bilin2<<<(BB * 9 * PP + 255) / 256, 256, 0, stream>>>(ppart, bp, idx4, wgt4);
    k_xt<<<dim3(144, 4, BB), 256, 0, stream>>>(x, xT);
    k_dconv<<<1152, 256, 0, stream>>>(xT, wt2h, wt2l, idx4, wgt4, qpart);
    k_gemm_bf<<<576, 256, 0, stream>>>(x, wq2h, wq2l, kv, 2, 256, 0, 0, npart);
    k_attn_part<<<dim3(NCH, HEADS, BB), 256, 0, stream>>>(qpart, kv, apart);
    k_attn_fin_w2<<<dim3(HEADS, BB), 256, 0, stream>>>(apart, npart, temp, wproj, w2h, w2l);
    k_gemm_bf<<<288, 256, 0, stream>>>(kv, w2h, w2l, out, 1, 512, 256, 65536, nullptr);
}

// Round 16
// 257.298 us; speedup vs baseline: 3.3477x; 1.0387x over previous
//
#include <hip/hip_runtime.h>
#include <math.h>

#define BB 2
#define CC 256
#define HW 96
#define PP 9216
#define KO 18
#define HEADS 8
#define NCH 18

typedef short bf16x8 __attribute__((ext_vector_type(8)));
typedef float f32x4 __attribute__((ext_vector_type(4)));

// ws layout (float offsets), lifetime-aliased
#define NP_O    0UL          // norm partials 4*144*256 = 147456
#define W2_O    147456UL     // W2 hi+lo (2 batches) = 131072 -> ends 278528
#define IDX_O   331776UL     // int4 table 663552 (dead after dconv)
#define WGT_O   995328UL     // float4 table 663552 (dead after dconv)
#define WT2_O   1658880UL    // wt2 hi+lo = 589824 (dead after dconv)
#define WP2_O   2248704UL    // wp2 hi+lo = 73728 (dead after pconv)
#define WQ2_O   2322432UL    // wq2 hi+lo = 131072 (dead after qkv)
#define QP_O    2584576UL    // qpart 9437184 (aliases ppart; dead after attn_part)
#define KV_O    12021760UL   // xT (4718592, lives bilin_xt..dconv) then k,v fp32 (9437184)
#define AP_O    21459968UL   // attn partials 2*8*18*1024 = 294912

__device__ __forceinline__ ushort f2bf_rne(float f) {
    unsigned u = __float_as_uint(f);
    unsigned r = (u + 0x7FFFu + ((u >> 16) & 1u)) >> 16;
    return (ushort)r;
}
__device__ __forceinline__ float bf2f(ushort h) {
    return __uint_as_float(((unsigned)h) << 16);
}

// ---- merged weight prep: wt (2304 blocks) | wp (288) | wq (512) ----
__global__ __launch_bounds__(256) void k_prep_all(const float* __restrict__ wd,
                                                  const float* __restrict__ wp,
                                                  const float* __restrict__ wqk,
                                                  ushort* __restrict__ wt2h, ushort* __restrict__ wt2l,
                                                  ushort* __restrict__ wp2h, ushort* __restrict__ wp2l,
                                                  ushort* __restrict__ wq2h, ushort* __restrict__ wq2l) {
    int blk = blockIdx.x;
    int t = threadIdx.x;
    if (blk < 2304) {
        int tid = blk * 256 + t;
        int e = tid & 7;
        int u = (tid >> 3) & 1023;
        int cs = (tid >> 13) & 7;
        int kk = tid >> 16;
        int oh = u >> 6, rem = u & 63;
        int lrow = rem & 15, lhi = rem >> 4;
        int o = oh * 16 + lrow;
        int c = cs * 32 + lhi * 8 + e;
        float v = wd[o * 2304 + c * 9 + kk];
        ushort hh = f2bf_rne(v);
        wt2h[tid] = hh;
        wt2l[tid] = f2bf_rne(v - bf2f(hh));
    } else if (blk < 2592) {
        int tid = (blk - 2304) * 256 + t;
        int e = tid & 7;
        int u = (tid >> 3) & 127;
        int cs = (tid >> 10) & 7;
        int kk = tid >> 13;
        int mf = u >> 6, rem = u & 63;
        int lrow = rem & 15, lhi = rem >> 4;
        int o = mf * 16 + lrow;
        int c = cs * 32 + lhi * 8 + e;
        float v = (o < KO) ? wp[(o * 256 + c) * 9 + kk] : 0.f;
        ushort hh = f2bf_rne(v);
        wp2h[tid] = hh;
        wp2l[tid] = f2bf_rne(v - bf2f(hh));
    } else {
        int tid = (blk - 2592) * 256 + t;
        int e = tid & 7;
        int u = (tid >> 3) & 1023;
        int csg = (tid >> 13) & 7;
        int mt = tid >> 16;
        int rem = u & 63;
        int lrow = rem & 15, lhi = rem >> 4;
        int o = mt * 256 + (u >> 6) * 16 + lrow;
        int c = csg * 32 + lhi * 8 + e;
        float v = wqk[o * 256 + c];
        ushort hh = f2bf_rne(v);
        wq2h[tid] = hh;
        wq2l[tid] = f2bf_rne(v - bf2f(hh));
    }
}

// ---- pconv MFMA, XCD-swizzled 1D grid of 1152 ----
__global__ __launch_bounds__(256) void k_pconv(const float* __restrict__ x,
                                               const ushort* __restrict__ wp2h,
                                               const ushort* __restrict__ wp2l,
                                               float* __restrict__ ppart) {
    int s = blockIdx.x;
    int xcd = s & 7;
    int b = xcd & 1, ks = xcd >> 1;
    int p0 = (s >> 3) * 64;
    int t = threadIdx.x;
    int l = t & 63, w = t >> 6;
    int lrow = l & 15, lhi = l >> 4;
    int p = t & 63, cg = t >> 6;
    __shared__ __align__(16) ushort Sh[64 * 40];
    __shared__ __align__(16) ushort Sl[64 * 40];
    f32x4 acc[2];
    acc[0] = (f32x4)0.f; acc[1] = (f32x4)0.f;
    const float* xb = x + (size_t)b * CC * PP;
    int pix = p0 + p;
    int i_ = pix / 96, j_ = pix % 96;
#pragma unroll 1
    for (int cs = 0; cs < 2; ++cs) {
        int csg = ks * 2 + cs;
        const float* xc0 = xb + (size_t)(csg * 32 + cg * 8) * PP;
#pragma unroll 1
        for (int kk = 0; kk < 9; ++kk) {
            int di = kk / 3 - 1, dj = kk % 3 - 1;
            bool vOK = ((unsigned)(i_ + di) < 96u) && ((unsigned)(j_ + dj) < 96u);
            int poff = pix + di * 96 + dj;
            __syncthreads();
            bf16x8 ah[2], al[2];
#pragma unroll
            for (int mf = 0; mf < 2; ++mf) {
                size_t gi = (((size_t)(kk * 8 + csg)) * 128 + (mf * 64 + l)) * 8;
                ah[mf] = *(const bf16x8*)&wp2h[gi];
                al[mf] = *(const bf16x8*)&wp2l[gi];
            }
            bf16x8 vh, vl;
#pragma unroll
            for (int i = 0; i < 8; ++i) {
                float v = vOK ? xc0[(size_t)i * PP + poff] : 0.f;
                ushort hh = f2bf_rne(v);
                vh[i] = (short)hh;
                vl[i] = (short)f2bf_rne(v - bf2f(hh));
            }
            *(bf16x8*)&Sh[p * 40 + cg * 8] = vh;
            *(bf16x8*)&Sl[p * 40 + cg * 8] = vl;
            __syncthreads();
            bf16x8 Bh = *(const bf16x8*)&Sh[(w * 16 + lrow) * 40 + lhi * 8];
            bf16x8 Bl = *(const bf16x8*)&Sl[(w * 16 + lrow) * 40 + lhi * 8];
#pragma unroll
            for (int mf = 0; mf < 2; ++mf) {
                acc[mf] = __builtin_amdgcn_mfma_f32_16x16x32_bf16(ah[mf], Bh, acc[mf], 0, 0, 0);
                acc[mf] = __builtin_amdgcn_mfma_f32_16x16x32_bf16(ah[mf], Bl, acc[mf], 0, 0, 0);
                acc[mf] = __builtin_amdgcn_mfma_f32_16x16x32_bf16(al[mf], Bh, acc[mf], 0, 0, 0);
            }
        }
    }
    float* pr = ppart + ((size_t)(ks * BB + b) * 32) * PP;
#pragma unroll
    for (int mf = 0; mf < 2; ++mf)
#pragma unroll
        for (int j = 0; j < 4; ++j)
            pr[(size_t)(mf * 16 + lhi * 4 + j) * PP + p0 + w * 16 + lrow] = acc[mf][j];
}

// ---- merged: bilinear table (648 blocks) | x->xT transpose (1152 blocks) ----
__global__ __launch_bounds__(256) void k_bilin_xt(const float* __restrict__ pp,
                                                  const float* __restrict__ bp,
                                                  int4* __restrict__ idx4,
                                                  float4* __restrict__ wgt4,
                                                  const float* __restrict__ x,
                                                  float* __restrict__ xT) {
    int blk = blockIdx.x;
    int t = threadIdx.x;
    if (blk < 648) {
        int idx = blk * 256 + t;
        if (idx >= BB * 9 * PP) return;
        int p = idx % PP;
        int bn = idx / PP;
        int n = bn % 9, b = bn / 9;
        int i = p / 96, j = p % 96;
        float ox = bp[n], oy = bp[n + 9];
#pragma unroll
        for (int k = 0; k < 4; ++k) {
            ox += pp[((size_t)(k * BB + b) * 32 + n) * PP + p];
            oy += pp[((size_t)(k * BB + b) * 32 + n + 9) * PP + p];
        }
        float px = ox + (float)(n / 3 - 1) + (float)(i + 1);
        float py = oy + (float)(n % 3 - 1) + (float)(j + 1);
        float fx = floorf(px), fy = floorf(py);
        float qltx = fminf(fmaxf(fx, 0.f), 97.f);
        float qlty = fminf(fmaxf(fy, 0.f), 97.f);
        float qrbx = fminf(fmaxf(fx + 1.f, 0.f), 97.f);
        float qrby = fminf(fmaxf(fy + 1.f, 0.f), 97.f);
        float pxc = fminf(fmaxf(px, 0.f), 97.f);
        float pyc = fminf(fmaxf(py, 0.f), 97.f);
        float glt = (1.f + (qltx - pxc)) * (1.f + (qlty - pyc));
        float grb = (1.f - (qrbx - pxc)) * (1.f - (qrby - pyc));
        float glb = (1.f + (qltx - pxc)) * (1.f - (qrby - pyc));
        float grt = (1.f - (qrbx - pxc)) * (1.f + (qlty - pyc));
        int x0 = (int)qltx - 1, y0 = (int)qlty - 1;
        int x1 = (int)qrbx - 1, y1 = (int)qrby - 1;
        bool vlt = (x0 >= 0 && x0 < 96 && y0 >= 0 && y0 < 96);
        bool vrb = (x1 >= 0 && x1 < 96 && y1 >= 0 && y1 < 96);
        bool vlb = (x0 >= 0 && x0 < 96 && y1 >= 0 && y1 < 96);
        bool vrt = (x1 >= 0 && x1 < 96 && y0 >= 0 && y0 < 96);
        int4 id;
        id.x = vlt ? x0 * 96 + y0 : 0;
        id.y = vrb ? x1 * 96 + y1 : 0;
        id.z = vlb ? x0 * 96 + y1 : 0;
        id.w = vrt ? x1 * 96 + y0 : 0;
        idx4[idx] = id;
        wgt4[idx] = make_float4(vlt ? glt : 0.f, vrb ? grb : 0.f,
                                vlb ? glb : 0.f, vrt ? grt : 0.f);
    } else {
        int s2 = blk - 648;
        int pt = s2 % 144;
        int ct = (s2 / 144) & 3;
        int b = s2 / 576;
        __shared__ float T[64][65];
        {
            int c = t >> 2, pq = (t & 3) * 16;
            const float* src = x + ((size_t)b * CC + ct * 64 + c) * PP + pt * 64 + pq;
#pragma unroll
            for (int k2 = 0; k2 < 4; ++k2) {
                float4 v = *(const float4*)&src[k2 * 4];
                T[c][pq + k2 * 4 + 0] = v.x;
                T[c][pq + k2 * 4 + 1] = v.y;
                T[c][pq + k2 * 4 + 2] = v.z;
                T[c][pq + k2 * 4 + 3] = v.w;
            }
        }
        __syncthreads();
        {
            int p = t >> 2, cq = (t & 3) * 16;
            float* dst = xT + ((size_t)b * PP + pt * 64 + p) * CC + ct * 64 + cq;
#pragma unroll
            for (int k2 = 0; k2 < 4; ++k2)
                *(float4*)&dst[k2 * 4] = make_float4(T[cq + k2 * 4 + 0][p], T[cq + k2 * 4 + 1][p],
                                                     T[cq + k2 * 4 + 2][p], T[cq + k2 * 4 + 3][p]);
        }
    }
}

// ---- dconv MFMA: BN=32 grid 1152, float4 gathers, 2-step phases over 36 steps ----
__global__ __launch_bounds__(256) void k_dconv(const float* __restrict__ xT,
                                               const ushort* __restrict__ wt2h,
                                               const ushort* __restrict__ wt2l,
                                               const int4* __restrict__ idx4,
                                               const float4* __restrict__ wgt4,
                                               float* __restrict__ qpart) {
    int s = blockIdx.x;
    int xcd = s & 7, ib = s >> 3;
    int combo = xcd >> 1;
    int b = combo & 1;
    int half = combo >> 1;
    int ptile = (xcd & 1) * 144 + ib;
    int p0 = ptile * 32;
    int t = threadIdx.x;
    int l = t & 63, w = t >> 6;
    int lrow = l & 15, lhi = l >> 4;
    int obase = w * 64;
    int pl = t & 31, cg = t >> 5;

    __shared__ __align__(16) ushort SH[4][1280], SL[4][1280];
    __shared__ int4 Tid[9 * 32];
    __shared__ float4 Twg[9 * 32];

    for (int e = t; e < 9 * 32; e += 256) {
        int kk = e >> 5, pq = e & 31;
        size_t tb = ((size_t)b * 9 + kk) * PP + p0 + pq;
        Tid[e] = idx4[tb];
        Twg[e] = wgt4[tb];
    }

    f32x4 acc[4][2];
#pragma unroll
    for (int mf = 0; mf < 4; ++mf)
#pragma unroll
        for (int nf = 0; nf < 2; ++nf) acc[mf][nf] = (f32x4)0.f;

    const float* xTb = xT + (size_t)b * PP * CC;
    int h4 = half * 4;

    float R0[16], R1[16];
    float4 g0, g1;

    auto LD = [&](int i, float (&R)[16], float4& g) {
        int cs = i / 9, kk = i % 9;          // i in [0,36): cs in 0..3
        int csg = h4 + cs;
        int4 id = Tid[kk * 32 + pl];
        g = Twg[kk * 32 + pl];
        const float* xt0 = xTb + (size_t)(csg * 32 + cg * 4);
        *(float4*)&R[0]  = *(const float4*)&xt0[(size_t)id.x * CC];
        *(float4*)&R[4]  = *(const float4*)&xt0[(size_t)id.y * CC];
        *(float4*)&R[8]  = *(const float4*)&xt0[(size_t)id.z * CC];
        *(float4*)&R[12] = *(const float4*)&xt0[(size_t)id.w * CC];
    };
    auto CONV = [&](const float (&R)[16], float4 g, ushort* Sh, ushort* Sl) {
        ushort4 vh, vl;
#pragma unroll
        for (int q = 0; q < 4; ++q) {
            float v = g.x * R[q];
            v = fmaf(g.y, R[4 + q], v);
            v = fmaf(g.z, R[8 + q], v);
            v = fmaf(g.w, R[12 + q], v);
            ushort hh = f2bf_rne(v);
            ushort ll = f2bf_rne(v - bf2f(hh));
            if (q == 0)      { vh.x = hh; vl.x = ll; }
            else if (q == 1) { vh.y = hh; vl.y = ll; }
            else if (q == 2) { vh.z = hh; vl.z = ll; }
            else             { vh.w = hh; vl.w = ll; }
        }
        *(ushort4*)&Sh[pl * 40 + cg * 4] = vh;
        *(ushort4*)&Sl[pl * 40 + cg * 4] = vl;
    };
    auto COMPUTE = [&](int i, const ushort* Sh, const ushort* Sl) {
        int cs = i / 9, kk = i % 9;
        int csg = h4 + cs;
        bf16x8 ah[4], al[4];
#pragma unroll
        for (int mf = 0; mf < 4; ++mf) {
            size_t gi = (((size_t)(kk * 8 + csg)) * 1024 + ((w * 4 + mf) * 64 + l)) * 8;
            ah[mf] = *(const bf16x8*)&wt2h[gi];
            al[mf] = *(const bf16x8*)&wt2l[gi];
        }
        bf16x8 Bh2[2], Bl2[2];
#pragma unroll
        for (int nf = 0; nf < 2; ++nf) {
            Bh2[nf] = *(const bf16x8*)&Sh[(nf * 16 + lrow) * 40 + lhi * 8];
            Bl2[nf] = *(const bf16x8*)&Sl[(nf * 16 + lrow) * 40 + lhi * 8];
        }
        __builtin_amdgcn_s_setprio(1);
#pragma unroll
        for (int mf = 0; mf < 4; ++mf)
#pragma unroll
            for (int nf = 0; nf < 2; ++nf) {
                acc[mf][nf] = __builtin_amdgcn_mfma_f32_16x16x32_bf16(ah[mf], Bh2[nf], acc[mf][nf], 0, 0, 0);
                acc[mf][nf] = __builtin_amdgcn_mfma_f32_16x16x32_bf16(ah[mf], Bl2[nf], acc[mf][nf], 0, 0, 0);
                acc[mf][nf] = __builtin_amdgcn_mfma_f32_16x16x32_bf16(al[mf], Bh2[nf], acc[mf][nf], 0, 0, 0);
            }
        __builtin_amdgcn_s_setprio(0);
    };

    __syncthreads();                 // tables ready
    LD(0, R0, g0); LD(1, R1, g1);
    CONV(R0, g0, SH[0], SL[0]);
    CONV(R1, g1, SH[1], SL[1]);
    LD(2, R0, g0); LD(3, R1, g1);
    __syncthreads();                 // pair0 ready; steps 2,3 raws in flight

#pragma unroll 1
    for (int ph = 0; ph < 18; ++ph) {       // 18 phases x 2 steps = 36 (cs 0..3, kk 0..8)
        int s0 = ph * 2;
        int cur = (ph & 1) * 2;
        int nxt = ((ph + 1) & 1) * 2;
        if (s0 + 2 < 36) CONV(R0, g0, SH[nxt], SL[nxt]);
        if (s0 + 3 < 36) CONV(R1, g1, SH[nxt + 1], SL[nxt + 1]);
        if (s0 + 4 < 36) LD(s0 + 4, R0, g0);    // drains under COMPUTE x2
        if (s0 + 5 < 36) LD(s0 + 5, R1, g1);
        COMPUTE(s0, SH[cur], SL[cur]);
        COMPUTE(s0 + 1, SH[cur + 1], SL[cur + 1]);
        __syncthreads();             // one barrier per 2 steps
    }

    float* qh = qpart + (size_t)half * BB * CC * PP + (size_t)b * CC * PP;
#pragma unroll
    for (int mf = 0; mf < 4; ++mf)
#pragma unroll
        for (int nf = 0; nf < 2; ++nf)
#pragma unroll
            for (int j = 0; j < 4; ++j)
                qh[(size_t)(obase + mf * 16 + lhi * 4 + j) * PP + p0 + nf * 16 + lrow] =
                    acc[mf][nf][j];
}

// ---- generic MFMA GEMM; B from fp32 (convert in-kernel) ----
__global__ __launch_bounds__(256) void k_gemm_bf(const float* __restrict__ Bsrc,
                                                 const ushort* __restrict__ A2h,
                                                 const ushort* __restrict__ A2l,
                                                 float* __restrict__ C,
                                                 int mtiles, int bRowStride, int bRowOff,
                                                 int aBatchStride,
                                                 float* __restrict__ npart) {
    int s = blockIdx.x;
    int xcd = s & 7, ib = s >> 3;
    int b, mt, ptile;
    if (mtiles == 2) {
        int combo = xcd >> 1;
        b = combo & 1; mt = combo >> 1;
        ptile = (xcd & 1) * 72 + ib;
    } else {
        b = xcd >> 2; mt = 0;
        ptile = (xcd & 3) * 36 + ib;
    }
    int p0 = ptile * 64;
    int t = threadIdx.x;
    int l = t & 63, w = t >> 6;
    int lrow = l & 15, lhi = l >> 4;
    int obase = w * 64;
    int p = t & 63, cg = t >> 6;
    __shared__ __align__(16) ushort Sh[64 * 40];
    __shared__ __align__(16) ushort Sl[64 * 40];
    f32x4 acc[4][4];
#pragma unroll
    for (int mf = 0; mf < 4; ++mf)
#pragma unroll
        for (int nf = 0; nf < 4; ++nf) acc[mf][nf] = (f32x4)0.f;
    const float* Bb = Bsrc + ((size_t)b * bRowStride + bRowOff) * PP;
    const ushort* Ah = A2h + (size_t)b * aBatchStride;
    const ushort* Al = A2l + (size_t)b * aBatchStride;
#pragma unroll 1
    for (int csg = 0; csg < 8; ++csg) {
        __syncthreads();
        bf16x8 ah[4], al[4];
#pragma unroll
        for (int mf = 0; mf < 4; ++mf) {
            size_t gi = (((size_t)(mt * 8 + csg)) * 1024 + ((w * 4 + mf) * 64 + l)) * 8;
            ah[mf] = *(const bf16x8*)&Ah[gi];
            al[mf] = *(const bf16x8*)&Al[gi];
        }
        const float* xr = Bb + (size_t)(csg * 32 + cg * 8) * PP + p0 + p;
        bf16x8 vh, vl;
#pragma unroll
        for (int i = 0; i < 8; ++i) {
            float v = xr[(size_t)i * PP];
            ushort hh = f2bf_rne(v);
            vh[i] = (short)hh;
            vl[i] = (short)f2bf_rne(v - bf2f(hh));
        }
        *(bf16x8*)&Sh[p * 40 + cg * 8] = vh;
        *(bf16x8*)&Sl[p * 40 + cg * 8] = vl;
        __syncthreads();
        bf16x8 Bh4[4], Bl4[4];
#pragma unroll
        for (int nf = 0; nf < 4; ++nf) {
            Bh4[nf] = *(const bf16x8*)&Sh[(nf * 16 + lrow) * 40 + lhi * 8];
            Bl4[nf] = *(const bf16x8*)&Sl[(nf * 16 + lrow) * 40 + lhi * 8];
        }
#pragma unroll
        for (int mf = 0; mf < 4; ++mf) {
#pragma unroll
            for (int nf = 0; nf < 4; ++nf) {
                acc[mf][nf] = __builtin_amdgcn_mfma_f32_16x16x32_bf16(ah[mf], Bh4[nf], acc[mf][nf], 0, 0, 0);
                acc[mf][nf] = __builtin_amdgcn_mfma_f32_16x16x32_bf16(ah[mf], Bl4[nf], acc[mf][nf], 0, 0, 0);
                acc[mf][nf] = __builtin_amdgcn_mfma_f32_16x16x32_bf16(al[mf], Bh4[nf], acc[mf][nf], 0, 0, 0);
            }
        }
    }
    float* Cb = C + (size_t)b * (mtiles * 256) * PP;
#pragma unroll
    for (int mf = 0; mf < 4; ++mf)
#pragma unroll
        for (int nf = 0; nf < 4; ++nf)
#pragma unroll
            for (int j = 0; j < 4; ++j)
                Cb[(size_t)(mt * 256 + obase + mf * 16 + lhi * 4 + j) * PP + p0 + nf * 16 + lrow] =
                    acc[mf][nf][j];
    if (npart) {
        float sq[4][4];
#pragma unroll
        for (int mf = 0; mf < 4; ++mf)
#pragma unroll
            for (int j = 0; j < 4; ++j) {
                float v0 = acc[mf][0][j], v1 = acc[mf][1][j];
                float v2 = acc[mf][2][j], v3 = acc[mf][3][j];
                sq[mf][j] = v0 * v0 + v1 * v1 + v2 * v2 + v3 * v3;
            }
#pragma unroll
        for (int m = 1; m <= 8; m <<= 1)
#pragma unroll
            for (int mf = 0; mf < 4; ++mf)
#pragma unroll
                for (int j = 0; j < 4; ++j)
                    sq[mf][j] += __shfl_xor(sq[mf][j], m, 64);
        if (lrow == 0) {
            float* np = npart + ((size_t)(b * 2 + mt) * 144 + ptile) * 256;
#pragma unroll
            for (int mf = 0; mf < 4; ++mf)
#pragma unroll
                for (int j = 0; j < 4; ++j)
                    np[obase + mf * 16 + lhi * 4 + j] = sq[mf][j];
        }
    }
}

// ---- attention score partials: q . k over 512-p chunks (NCH=18) ----
__global__ __launch_bounds__(256) void k_attn_part(const float* __restrict__ qp,
                                                   const float* __restrict__ kv,
                                                   float* __restrict__ apart) {
    int ch = blockIdx.x, h = blockIdx.y, b = blockIdx.z;
    int t = threadIdx.x;
    int d = t & 31, cg = t >> 5;
    __shared__ float qs[32][37], ks[32][37];
    float acc[4] = {0.f, 0.f, 0.f, 0.f};
    const float* q0 = qp + ((size_t)b * CC + h * 32) * PP;
    const float* q1 = q0 + (size_t)BB * CC * PP;
    const float* kb = kv + ((size_t)b * 512 + h * 32) * PP;
    int r = t >> 3, cq = (t & 7) * 4;
    for (int po = ch * 512; po < ch * 512 + 512; po += 32) {
        float4 va = *(const float4*)&q0[(size_t)r * PP + po + cq];
        float4 vb = *(const float4*)&q1[(size_t)r * PP + po + cq];
        qs[r][cq + 0] = va.x + vb.x; qs[r][cq + 1] = va.y + vb.y;
        qs[r][cq + 2] = va.z + vb.z; qs[r][cq + 3] = va.w + vb.w;
        float4 vk = *(const float4*)&kb[(size_t)r * PP + po + cq];
        ks[r][cq + 0] = vk.x; ks[r][cq + 1] = vk.y;
        ks[r][cq + 2] = vk.z; ks[r][cq + 3] = vk.w;
        __syncthreads();
#pragma unroll
        for (int pq = 0; pq < 32; ++pq) {
            float kvv = ks[d][pq];
#pragma unroll
            for (int i = 0; i < 4; ++i)
                acc[i] = fmaf(qs[cg * 4 + i][pq], kvv, acc[i]);
        }
        __syncthreads();
    }
    float* ap = apart + (((size_t)(b * 8 + h) * NCH + ch) << 10);
#pragma unroll
    for (int i = 0; i < 4; ++i) ap[(cg * 4 + i) * 32 + d] = acc[i];
}

// ---- merged: norms + reduce + softmax + W2 = Wproj-slice @ As ----
__global__ __launch_bounds__(256) void k_attn_fin_w2(const float* __restrict__ apart,
                                                     const float* __restrict__ npart,
                                                     const float* __restrict__ temp,
                                                     const float* __restrict__ wproj,
                                                     ushort* __restrict__ w2h,
                                                     ushort* __restrict__ w2l) {
    int h = blockIdx.x, b = blockIdx.y;
    int t = threadIdx.x;
    __shared__ float A[32][33];
    __shared__ float invk[32], invv[32];
    if (t < 64) {
        int mt = t >> 5, row = (t & 31) + h * 32;
        const float* base = npart + ((size_t)(b * 2 + mt) * 144) * 256 + row;
        float ssum = 0.f;
        for (int pt = 0; pt < 144; ++pt) ssum += base[pt * 256];
        float iv = 1.f / fmaxf(sqrtf(ssum), 1e-12f);
        if (mt == 0) invk[t & 31] = iv; else invv[t & 31] = iv;
    }
    const float* ap = apart + ((size_t)(b * 8 + h) * NCH << 10);
    float th = temp[h];
    for (int e = t; e < 1024; e += 256) {
        float s = 0.f;
        for (int chn = 0; chn < NCH; ++chn) s += ap[chn * 1024 + e];
        A[e >> 5][e & 31] = s * th;
    }
    __syncthreads();
    if (t < 32) {
        int c = t;
        float m = -INFINITY;
        float row[32];
#pragma unroll
        for (int d = 0; d < 32; ++d) {
            row[d] = A[c][d] * invk[d];
            m = fmaxf(m, row[d]);
        }
        float sum = 0.f;
#pragma unroll
        for (int d = 0; d < 32; ++d) sum += expf(row[d] - m);
        float inv = 1.f / sum;
#pragma unroll
        for (int d = 0; d < 32; ++d)
            A[c][d] = expf(row[d] - m) * inv * invv[d];
    }
    __syncthreads();
    int o = t;
    float wrow[32];
#pragma unroll
    for (int c = 0; c < 32; ++c) wrow[c] = wproj[o * 256 + h * 32 + c];
    int wq = o >> 6, mf = (o >> 4) & 3, lr = o & 15;
    size_t bb = (size_t)b * 65536;
#pragma unroll
    for (int e = 0; e < 32; ++e) {
        float v = 0.f;
#pragma unroll
        for (int c = 0; c < 32; ++c) v = fmaf(wrow[c], A[c][e], v);
        int lhi = e >> 3, ee = e & 7;
        size_t gi = bb + ((size_t)h * 1024 + ((wq * 4 + mf) * 64 + lhi * 16 + lr)) * 8 + ee;
        ushort hh = f2bf_rne(v);
        w2h[gi] = hh;
        w2l[gi] = f2bf_rne(v - bf2f(hh));
    }
}

extern "C" void kernel_launch(void* const* d_in, const int* in_sizes, int n_in,
                              void* d_out, int out_size, void* d_ws, size_t ws_size,
                              hipStream_t stream) {
    const float* x     = (const float*)d_in[0];
    const float* wp    = (const float*)d_in[1];
    const float* bp    = (const float*)d_in[2];
    const float* wd    = (const float*)d_in[3];
    const float* wqkv  = (const float*)d_in[4];
    const float* temp  = (const float*)d_in[5];
    const float* wproj = (const float*)d_in[6];
    float* out = (float*)d_out;
    float* ws  = (float*)d_ws;

    float* npart  = ws + NP_O;
    ushort* w2h   = (ushort*)(ws + W2_O);
    ushort* w2l   = w2h + 2 * 65536;
    int4*  idx4   = (int4*)(ws + IDX_O);
    float4* wgt4  = (float4*)(ws + WGT_O);
    ushort* wt2h  = (ushort*)(ws + WT2_O);
    ushort* wt2l  = wt2h + 9 * 8 * 1024 * 8;
    ushort* wp2h  = (ushort*)(ws + WP2_O);
    ushort* wp2l  = wp2h + 9 * 8 * 128 * 8;
    ushort* wq2h  = (ushort*)(ws + WQ2_O);
    ushort* wq2l  = wq2h + 2 * 8 * 1024 * 8;
    float* qpart  = ws + QP_O;   // aliases ppart (sequential lifetimes)
    float* ppart  = ws + QP_O;
    float* xT     = ws + KV_O;   // lives [bilin_xt .. dconv]; kv overwrites after
    float* kv     = ws + KV_O;
    float* apart  = ws + AP_O;

    k_prep_all<<<3104, 256, 0, stream>>>(wd, wp, wqkv + 256 * 256,
                                         wt2h, wt2l, wp2h, wp2l, wq2h, wq2l);
    k_pconv<<<1152, 256, 0, stream>>>(x, wp2h, wp2l, ppart);
    k_bilin_xt<<<1800, 256, 0, stream>>>(ppart, bp, idx4, wgt4, x, xT);
    k_dconv<<<1152, 256, 0, stream>>>(xT, wt2h, wt2l, idx4, wgt4, qpart);
    k_gemm_bf<<<576, 256, 0, stream>>>(x, wq2h, wq2l, kv, 2, 256, 0, 0, npart);
    k_attn_part<<<dim3(NCH, HEADS, BB), 256, 0, stream>>>(qpart, kv, apart);
    k_attn_fin_w2<<<dim3(HEADS, BB), 256, 0, stream>>>(apart, npart, temp, wproj, w2h, w2l);
    k_gemm_bf<<<288, 256, 0, stream>>>(kv, w2h, w2l, out, 1, 512, 256, 65536, nullptr);
}